// Round 1
// baseline (2994.579 us; speedup 1.0000x reference)
//
#include <hip/hip_runtime.h>
#include <hip/hip_bf16.h>
#include <math.h>

// ---------------------------------------------------------------------------
// Mamba2 forward, MI355X. Round 0: correctness-first baseline.
//   K1 gemm64<bf16> : zxbcdt = u @ W_in            (fp32 in, bf16 out)
//   K2 dt_kernel    : dt = softplus(zxbcdt[...,-NH:] + dt_bias)
//   K3 conv_silu    : xbc_act = silu(causal_dwconv(xBC))
//   K4 chunk_state  : per-(b,chunk,head) end state  S[p,n], + chunk A-sum
//   K5 scan_kernel  : sequential inter-chunk scan (states -> states_in)
//   K6 y_kernel     : Y = (L o C.B^T) @ xd + exp(Acum) * C.S_in^T, gated
//   K7 ln_kernel    : LayerNorm over DI
//   K8 gemm64<float>: out = y_norm @ W_out
// Workspace: ~245 MB (zxbcdt/xbc/states in bf16 to stay under 256 MiB).
// ---------------------------------------------------------------------------

namespace {

constexpr int kB   = 2;
constexpr int kL   = 4096;
constexpr int kDI  = 2048;
constexpr int kDS  = 128;
constexpr int kNH  = 32;
constexpr int kHP  = 64;          // DI / NH
constexpr int kDC  = 4;
constexpr int kCS  = 64;
constexpr int kNC  = kL / kCS;    // 64
constexpr int kDProj   = 2 * kDI + 2 * kDS + kNH;  // 4384
constexpr int kConvDim = kDI + 2 * kDS;            // 2304
constexpr int kRows = kB * kL;    // 8192
constexpr float kEps = 1e-5f;
constexpr int kDSP = kDS + 4;     // padded LDS stride (132) to break 128-elem bank aliasing

__device__ inline float bf2f(__hip_bfloat16 v) { return __bfloat162float(v); }
__device__ inline __hip_bfloat16 f2bf(float v) { return __float2bfloat16(v); }

__device__ inline void store_out(float* C, size_t i, float v) { C[i] = v; }
__device__ inline void store_out(__hip_bfloat16* C, size_t i, float v) { C[i] = f2bf(v); }

// ---- K1/K8: simple LDS-tiled fp32 GEMM, 64x64 tile, 256 threads, 4x4/thread
template <typename OutT>
__global__ void gemm64(const float* __restrict__ A, const float* __restrict__ B,
                       OutT* __restrict__ C, int M, int N, int K) {
  __shared__ float As[16][65];
  __shared__ float Bs[16][65];
  const int tid = threadIdx.x;
  const int tx = tid & 15, ty = tid >> 4;
  const int m0 = blockIdx.y * 64, n0 = blockIdx.x * 64;
  float acc[4][4] = {};
  for (int k0 = 0; k0 < K; k0 += 16) {
#pragma unroll
    for (int i = 0; i < 4; i++) {
      int e = tid + i * 256;
      int ka = e & 15, ma = e >> 4;
      As[ka][ma] = A[(size_t)(m0 + ma) * K + k0 + ka];   // M%64==0, K%16==0
      int nb = e & 63, kb = e >> 6;
      Bs[kb][nb] = (n0 + nb < N) ? B[(size_t)(k0 + kb) * N + n0 + nb] : 0.f;
    }
    __syncthreads();
#pragma unroll
    for (int k = 0; k < 16; k++) {
      float a[4], b[4];
#pragma unroll
      for (int i = 0; i < 4; i++) a[i] = As[k][ty * 4 + i];
#pragma unroll
      for (int j = 0; j < 4; j++) b[j] = Bs[k][tx * 4 + j];
#pragma unroll
      for (int i = 0; i < 4; i++)
#pragma unroll
        for (int j = 0; j < 4; j++) acc[i][j] += a[i] * b[j];
    }
    __syncthreads();
  }
#pragma unroll
  for (int i = 0; i < 4; i++) {
    int m = m0 + ty * 4 + i;
#pragma unroll
    for (int j = 0; j < 4; j++) {
      int n = n0 + tx * 4 + j;
      if (n < N) store_out(C, (size_t)m * N + n, acc[i][j]);
    }
  }
}

// ---- K2: dt = softplus(dt_raw + dt_bias)
__global__ void dt_kernel(const __hip_bfloat16* __restrict__ zxbcdt,
                          const float* __restrict__ dt_bias,
                          float* __restrict__ dtbuf) {
  int idx = blockIdx.x * 256 + threadIdx.x;     // row*NH + h
  if (idx >= kRows * kNH) return;
  int row = idx >> 5, h = idx & 31;
  float x = bf2f(zxbcdt[(size_t)row * kDProj + (kDProj - kNH) + h]) + dt_bias[h];
  dtbuf[idx] = (x > 15.f) ? x : log1pf(expf(x));
}

// ---- K3: causal depthwise conv (k=4) + SiLU
__global__ void conv_silu_kernel(const __hip_bfloat16* __restrict__ zxbcdt,
                                 const float* __restrict__ conv_w,
                                 const float* __restrict__ conv_b,
                                 __hip_bfloat16* __restrict__ xbc_act) {
  int c = blockIdx.x * 256 + threadIdx.x;
  int row = blockIdx.y;
  if (c >= kConvDim) return;
  int b = row >> 12, l = row & (kL - 1);
  float acc = conv_b[c];
#pragma unroll
  for (int i = 0; i < kDC; i++) {
    int li = l - (kDC - 1) + i;
    if (li >= 0)
      acc += bf2f(zxbcdt[(size_t)(b * kL + li) * kDProj + kDI + c]) * conv_w[c * kDC + i];
  }
  float s = acc / (1.f + expf(-acc));
  xbc_act[(size_t)row * kConvDim + c] = f2bf(s);
}

// ---- K4: per-(b,chunk,head) end-of-chunk state S[p,n] = sum_s B[s,n]*decay[s]*x[s,p]*dt[s]
__global__ void chunk_state_kernel(const __hip_bfloat16* __restrict__ xbc_act,
                                   const float* __restrict__ dtbuf,
                                   const float* __restrict__ A_log,
                                   __hip_bfloat16* __restrict__ states,
                                   float* __restrict__ asum) {
  const int id = blockIdx.x;                 // (b*NC + c)*NH + h
  const int h = id & 31;
  const int c = (id >> 5) & (kNC - 1);
  const int b = id >> 11;
  const int tid = threadIdx.x;
  __shared__ float s_dt[kCS];
  __shared__ float s_acum[kCS];
  __shared__ float s_xdd[kCS * kHP];          // x*dt*decay, fp32
  __shared__ __hip_bfloat16 s_B[kCS * kDS];
  const int l0 = b * kL + c * kCS;
  if (tid < kCS) s_dt[tid] = dtbuf[(size_t)(l0 + tid) * kNH + h];
  __syncthreads();
  if (tid == 0) {
    float A = -expf(A_log[h]);
    float run = 0.f;
    for (int s = 0; s < kCS; s++) { run += A * s_dt[s]; s_acum[s] = run; }
    asum[id] = run;
  }
  __syncthreads();
  const float total = s_acum[kCS - 1];
  for (int e = tid; e < kCS * kDS; e += 256) {
    int s = e >> 7, n = e & 127;
    s_B[e] = xbc_act[(size_t)(l0 + s) * kConvDim + kDI + n];
  }
  for (int e = tid; e < kCS * kHP; e += 256) {
    int s = e >> 6, p = e & 63;
    float xv = bf2f(xbc_act[(size_t)(l0 + s) * kConvDim + h * kHP + p]);
    s_xdd[e] = xv * s_dt[s] * expf(total - s_acum[s]);
  }
  __syncthreads();
  const int p = tid >> 2;
  const int n0 = (tid & 3) * 32;
  float acc[32];
#pragma unroll
  for (int j = 0; j < 32; j++) acc[j] = 0.f;
  for (int s = 0; s < kCS; s++) {
    float xv = s_xdd[s * kHP + p];
#pragma unroll
    for (int j = 0; j < 32; j++) acc[j] += xv * bf2f(s_B[s * kDS + n0 + j]);
  }
  size_t base = ((size_t)id * kHP + p) * kDS + n0;
#pragma unroll
  for (int j = 0; j < 32; j++) states[base + j] = f2bf(acc[j]);
}

// ---- K5: sequential inter-chunk scan, in place: states[c] <- states_in[c]
__global__ void scan_kernel(__hip_bfloat16* __restrict__ states,
                            const float* __restrict__ asum) {
  const int blk = blockIdx.x;                // (b*NH + h)*32 + seg
  const int seg = blk & 31;
  const int bh = blk >> 5;
  const int h = bh & 31, b = bh >> 5;
  const int e = seg * 256 + threadIdx.x;     // element in [0, HP*DS)
  float carry = 0.f;
  for (int c = 0; c < kNC; c++) {
    const int id = (b * kNC + c) * kNH + h;
    size_t addr = (size_t)id * (kHP * kDS) + e;
    float decay = expf(asum[id]);
    float tmp = bf2f(states[addr]);
    states[addr] = f2bf(carry);
    carry = carry * decay + tmp;
  }
}

// ---- K6: intra-chunk Y + carried-state contribution + SiLU(z) gate
__global__ void y_kernel(const __hip_bfloat16* __restrict__ xbc_act,
                         const __hip_bfloat16* __restrict__ zxbcdt,
                         const __hip_bfloat16* __restrict__ states_in,
                         const float* __restrict__ dtbuf,
                         const float* __restrict__ A_log,
                         float* __restrict__ ybuf) {
  const int id = blockIdx.x;                 // (b*NC + c)*NH + h
  const int h = id & 31;
  const int c = (id >> 5) & (kNC - 1);
  const int b = id >> 11;
  const int tid = threadIdx.x;
  __shared__ __hip_bfloat16 s_B[kCS * kDSP]; // B tile; later reused for S_in[p][n]
  __shared__ __hip_bfloat16 s_C[kCS * kDSP];
  __shared__ __hip_bfloat16 s_xd[kCS * kHP]; // x*dt
  __shared__ float s_W[kCS * kCS];
  __shared__ float s_dt[kCS];
  __shared__ float s_acum[kCS];
  const int l0 = b * kL + c * kCS;
  if (tid < kCS) s_dt[tid] = dtbuf[(size_t)(l0 + tid) * kNH + h];
  __syncthreads();
  if (tid == 0) {
    float A = -expf(A_log[h]);
    float run = 0.f;
    for (int s = 0; s < kCS; s++) { run += A * s_dt[s]; s_acum[s] = run; }
  }
  __syncthreads();
  for (int e = tid; e < kCS * kDS; e += 256) {
    int s = e >> 7, n = e & 127;
    size_t rb = (size_t)(l0 + s) * kConvDim;
    s_B[s * kDSP + n] = xbc_act[rb + kDI + n];
    s_C[s * kDSP + n] = xbc_act[rb + kDI + kDS + n];
  }
  for (int e = tid; e < kCS * kHP; e += 256) {
    int s = e >> 6, p = e & 63;
    float xv = bf2f(xbc_act[(size_t)(l0 + s) * kConvDim + h * kHP + p]);
    s_xd[e] = f2bf(xv * s_dt[s]);
  }
  __syncthreads();
  // W[l][s] = (s<=l) ? exp(acum[l]-acum[s]) * dot(C_l, B_s) : 0
  for (int e = tid; e < kCS * kCS; e += 256) {
    int l = e >> 6, s = e & 63;
    float w = 0.f;
    if (s <= l) {
      float dot = 0.f;
      for (int n = 0; n < kDS; n++)
        dot += bf2f(s_C[l * kDSP + n]) * bf2f(s_B[s * kDSP + n]);
      w = dot * expf(s_acum[l] - s_acum[s]);
    }
    s_W[e] = w;
  }
  __syncthreads();
  // reuse s_B for S_in[p][n] (padded stride)
  for (int e = tid; e < kHP * kDS; e += 256) {
    int p = e >> 7, n = e & 127;
    s_B[p * kDSP + n] = states_in[(size_t)id * (kHP * kDS) + e];
  }
  __syncthreads();
  for (int e = tid; e < kCS * kHP; e += 256) {
    int l = e >> 6, p = e & 63;
    float acc = 0.f;
    for (int s = 0; s <= l; s++)
      acc += s_W[l * kCS + s] * bf2f(s_xd[s * kHP + p]);
    float off = 0.f;
    for (int n = 0; n < kDS; n++)
      off += bf2f(s_C[l * kDSP + n]) * bf2f(s_B[p * kDSP + n]);
    acc += off * expf(s_acum[l]);
    float z = bf2f(zxbcdt[(size_t)(l0 + l) * kDProj + h * kHP + p]);
    float g = z / (1.f + expf(-z));
    ybuf[(size_t)(l0 + l) * kDI + h * kHP + p] = acc * g;
  }
}

// ---- K7: LayerNorm over DI, in place
__global__ void ln_kernel(float* __restrict__ ybuf,
                          const float* __restrict__ norm_w,
                          const float* __restrict__ norm_b) {
  const int row = blockIdx.x;
  float* y = ybuf + (size_t)row * kDI;
  float s = 0.f, ss = 0.f;
  for (int i = threadIdx.x; i < kDI; i += 256) {
    float v = y[i];
    s += v; ss += v * v;
  }
#pragma unroll
  for (int off = 32; off > 0; off >>= 1) {
    s += __shfl_down(s, off);
    ss += __shfl_down(ss, off);
  }
  __shared__ float red[8];
  int lane = threadIdx.x & 63, wv = threadIdx.x >> 6;
  if (lane == 0) { red[wv] = s; red[4 + wv] = ss; }
  __syncthreads();
  if (threadIdx.x == 0) {
    float S = red[0] + red[1] + red[2] + red[3];
    float SS = red[4] + red[5] + red[6] + red[7];
    float mu = S / kDI;
    float var = SS / kDI - mu * mu;
    red[0] = mu;
    red[1] = rsqrtf(var + kEps);
  }
  __syncthreads();
  float mu = red[0], rstd = red[1];
  for (int i = threadIdx.x; i < kDI; i += 256)
    y[i] = (y[i] - mu) * rstd * norm_w[i] + norm_b[i];
}

}  // namespace

extern "C" void kernel_launch(void* const* d_in, const int* in_sizes, int n_in,
                              void* d_out, int out_size, void* d_ws, size_t ws_size,
                              hipStream_t stream) {
  const float* u       = (const float*)d_in[0];
  const float* W_in    = (const float*)d_in[1];
  const float* conv_w  = (const float*)d_in[2];
  const float* conv_b  = (const float*)d_in[3];
  const float* dt_bias = (const float*)d_in[4];
  const float* A_log   = (const float*)d_in[5];
  const float* norm_w  = (const float*)d_in[6];
  const float* norm_b  = (const float*)d_in[7];
  const float* W_out   = (const float*)d_in[8];
  float* out = (float*)d_out;

  char* ws = (char*)d_ws;
  size_t off = 0;
  auto alloc = [&](size_t bytes) {
    void* p = ws + off;
    off += (bytes + 255) & ~(size_t)255;
    return p;
  };
  __hip_bfloat16* zxbcdt = (__hip_bfloat16*)alloc((size_t)kRows * kDProj * 2);    // 71.8 MB
  __hip_bfloat16* xbc    = (__hip_bfloat16*)alloc((size_t)kRows * kConvDim * 2);  // 37.7 MB
  float* dtb             = (float*)alloc((size_t)kRows * kNH * 4);                //  1.0 MB
  float* asum            = (float*)alloc((size_t)kB * kNC * kNH * 4);             // 16 KB
  __hip_bfloat16* states = (__hip_bfloat16*)alloc((size_t)kB * kNC * kNH * kHP * kDS * 2); // 67.1 MB
  float* ybuf            = (float*)alloc((size_t)kRows * kDI * 4);                // 67.1 MB
  (void)ws_size; (void)in_sizes; (void)n_in; (void)out_size;

  // K1: zxbcdt = u @ W_in   (M=8192, N=4384, K=1024)
  gemm64<__hip_bfloat16><<<dim3((kDProj + 63) / 64, kRows / 64), 256, 0, stream>>>(
      u, W_in, zxbcdt, kRows, kDProj, 1024);
  // K2: dt
  dt_kernel<<<(kRows * kNH + 255) / 256, 256, 0, stream>>>(zxbcdt, dt_bias, dtb);
  // K3: conv + silu
  conv_silu_kernel<<<dim3(kConvDim / 256, kRows), 256, 0, stream>>>(zxbcdt, conv_w, conv_b, xbc);
  // K4: per-chunk states
  chunk_state_kernel<<<kB * kNC * kNH, 256, 0, stream>>>(xbc, dtb, A_log, states, asum);
  // K5: inter-chunk scan
  scan_kernel<<<kB * kNH * 32, 256, 0, stream>>>(states, asum);
  // K6: Y (diag + off-diag) + gate
  y_kernel<<<kB * kNC * kNH, 256, 0, stream>>>(xbc, zxbcdt, states, dtb, A_log, ybuf);
  // K7: LayerNorm
  ln_kernel<<<kRows, 256, 0, stream>>>(ybuf, norm_w, norm_b);
  // K8: out = y_norm @ W_out  (M=8192, N=1024, K=2048)
  gemm64<float><<<dim3(1024 / 64, kRows / 64), 256, 0, stream>>>(ybuf, W_out, out, kRows, 1024, 2048);
}

// Round 3
// 1126.894 us; speedup vs baseline: 2.6574x; 2.6574x over previous
//
#include <hip/hip_runtime.h>
#include <hip/hip_bf16.h>
#include <math.h>

// ---------------------------------------------------------------------------
// Mamba2 forward, MI355X. Round 3: round-2 MFMA pipeline hardened:
//  - explicit s_waitcnt vmcnt(0) before the staging barrier in gemm_bt
//  - zero workspace aliasing (each buffer private), LN in-place (no ybn)
// Pipeline:
//   C0 cast_u, C1 transpose_cast(W_in), K1 gemm_bt -> zxbcdt (bf16)
//   K2 dt, K3 conv+silu, K4 chunk_state, K5 scan, K6 y(+gate) bf16
//   C2 transpose_cast(W_out), K7 LN in-place, K8 gemm_bt -> out (fp32)
// Workspace ~230 MiB.
// ---------------------------------------------------------------------------

namespace {

constexpr int kB   = 2;
constexpr int kL   = 4096;
constexpr int kDI  = 2048;
constexpr int kDS  = 128;
constexpr int kNH  = 32;
constexpr int kHP  = 64;
constexpr int kDC  = 4;
constexpr int kCS  = 64;
constexpr int kNC  = kL / kCS;
constexpr int kDProj   = 2 * kDI + 2 * kDS + kNH;  // 4384
constexpr int kDProjP  = 4480;                     // 35*128
constexpr int kConvDim = kDI + 2 * kDS;            // 2304
constexpr int kRows = kB * kL;                     // 8192
constexpr float kEps = 1e-5f;
constexpr int kDSP = kDS + 4;

typedef __bf16 bf16x8 __attribute__((ext_vector_type(8)));
typedef float f32x4 __attribute__((ext_vector_type(4)));

__device__ inline float bu2f(unsigned short u) {
  union { unsigned int i; float f; } x; x.i = ((unsigned int)u) << 16; return x.f;
}
__device__ inline unsigned short f2bu(float f) {
  __hip_bfloat16 h = __float2bfloat16(f);
  return *reinterpret_cast<unsigned short*>(&h);
}

__device__ inline void store_out(float* C, size_t i, float v) { C[i] = v; }
__device__ inline void store_out(unsigned short* C, size_t i, float v) { C[i] = f2bu(v); }

__device__ inline void gld_lds16(const unsigned short* g, unsigned short* l) {
  __builtin_amdgcn_global_load_lds(
      (const __attribute__((address_space(1))) unsigned int*)g,
      (__attribute__((address_space(3))) unsigned int*)l, 16, 0, 0);
}

// ---- cast fp32 -> bf16, 4 elems/thread
__global__ void cast_kernel(const float4* __restrict__ in, ushort4* __restrict__ out, int n4) {
  int i = blockIdx.x * 256 + threadIdx.x;
  if (i >= n4) return;
  float4 v = in[i];
  ushort4 o;
  o.x = f2bu(v.x); o.y = f2bu(v.y); o.z = f2bu(v.z); o.w = f2bu(v.w);
  out[i] = o;
}

// ---- transpose + cast: in[R][C] fp32 -> out[Cpad][R] bf16 (rows >= C zeroed)
__global__ void transpose_cast(const float* __restrict__ in, unsigned short* __restrict__ out,
                               int R, int C, int Cpad) {
  __shared__ float t[32][33];
  const int c0 = blockIdx.x * 32;
  const int r0 = blockIdx.y * 32;
  const int tx = threadIdx.x & 31, ty = threadIdx.x >> 5;  // 256 thr: ty 0..7
  for (int rr = ty; rr < 32; rr += 8) {
    int c = c0 + tx;
    t[rr][tx] = (c < C) ? in[(size_t)(r0 + rr) * C + c] : 0.f;
  }
  __syncthreads();
  for (int cc = ty; cc < 32; cc += 8) {
    int orow = c0 + cc;
    out[(size_t)orow * R + r0 + tx] = f2bu(t[tx][cc]);
  }
}

// ---- MFMA GEMM: C[M][N] = A[M][K] * Bt[N][K]^T, bf16 in, 128x128 tile.
template <typename OutT>
__global__ __launch_bounds__(256) void gemm_bt(const unsigned short* __restrict__ A,
                                               const unsigned short* __restrict__ Bt,
                                               OutT* __restrict__ C, int M, int N, int K) {
  __shared__ __align__(16) unsigned short As[128 * 32];
  __shared__ __align__(16) unsigned short Bs[128 * 32];
  const int tid = threadIdx.x;
  const int wave = tid >> 6, lane = tid & 63;
  const int m0 = blockIdx.y * 128, n0 = blockIdx.x * 128;
  const int wr = (wave >> 1) * 64, wc = (wave & 1) * 64;
  const int st_row = lane >> 2;
  const int st_col = (lane & 3) * 8;
  const unsigned short* pA[2];
  const unsigned short* pB[2];
  unsigned short* lA[2];
  unsigned short* lB[2];
#pragma unroll
  for (int r = 0; r < 2; r++) {
    int q = wave * 2 + r;
    pA[r] = A + (size_t)(m0 + q * 16 + st_row) * K + st_col;
    pB[r] = Bt + (size_t)(n0 + q * 16 + st_row) * K + st_col;
    lA[r] = &As[q * 512];
    lB[r] = &Bs[q * 512];
  }
  const int frag_row = lane & 15;
  const int frag_k = (lane >> 4) * 8;
  f32x4 acc[4][4] = {};
  for (int k0 = 0; k0 < K; k0 += 32) {
#pragma unroll
    for (int r = 0; r < 2; r++) {
      gld_lds16(pA[r] + k0, lA[r]);
      gld_lds16(pB[r] + k0, lB[r]);
    }
    // Explicit drain of the global->LDS DMA before any wave can cross the
    // barrier and read the staged data (defensive: do not rely on the
    // compiler's implicit vmcnt(0) at s_barrier).
    asm volatile("s_waitcnt vmcnt(0)" ::: "memory");
    __syncthreads();
    bf16x8 af[4], bfr[4];
#pragma unroll
    for (int i = 0; i < 4; i++)
      af[i] = *(const bf16x8*)&As[(wr + i * 16 + frag_row) * 32 + frag_k];
#pragma unroll
    for (int j = 0; j < 4; j++)
      bfr[j] = *(const bf16x8*)&Bs[(wc + j * 16 + frag_row) * 32 + frag_k];
#pragma unroll
    for (int i = 0; i < 4; i++)
#pragma unroll
      for (int j = 0; j < 4; j++)
        acc[i][j] = __builtin_amdgcn_mfma_f32_16x16x32_bf16(af[i], bfr[j], acc[i][j], 0, 0, 0);
    __syncthreads();
  }
  const int crow = (lane >> 4) * 4;
  const int ccol = lane & 15;
#pragma unroll
  for (int i = 0; i < 4; i++) {
#pragma unroll
    for (int j = 0; j < 4; j++) {
      int n = n0 + wc + j * 16 + ccol;
      if (n < N) {
#pragma unroll
        for (int r = 0; r < 4; r++) {
          int m = m0 + wr + i * 16 + crow + r;
          store_out(C, (size_t)m * N + n, acc[i][j][r]);
        }
      }
    }
  }
}

// ---- K2: dt = softplus(dt_raw + dt_bias)
__global__ void dt_kernel(const unsigned short* __restrict__ zxbcdt,
                          const float* __restrict__ dt_bias,
                          float* __restrict__ dtbuf) {
  int idx = blockIdx.x * 256 + threadIdx.x;
  if (idx >= kRows * kNH) return;
  int row = idx >> 5, h = idx & 31;
  float x = bu2f(zxbcdt[(size_t)row * kDProj + (kDProj - kNH) + h]) + dt_bias[h];
  dtbuf[idx] = (x > 15.f) ? x : log1pf(expf(x));
}

// ---- K3: causal depthwise conv (k=4) + SiLU
__global__ void conv_silu_kernel(const unsigned short* __restrict__ zxbcdt,
                                 const float* __restrict__ conv_w,
                                 const float* __restrict__ conv_b,
                                 unsigned short* __restrict__ xbc_act) {
  int c = blockIdx.x * 256 + threadIdx.x;
  int row = blockIdx.y;
  if (c >= kConvDim) return;
  int b = row >> 12, l = row & (kL - 1);
  float acc = conv_b[c];
#pragma unroll
  for (int i = 0; i < kDC; i++) {
    int li = l - (kDC - 1) + i;
    if (li >= 0)
      acc += bu2f(zxbcdt[(size_t)(b * kL + li) * kDProj + kDI + c]) * conv_w[c * kDC + i];
  }
  float s = acc / (1.f + expf(-acc));
  xbc_act[(size_t)row * kConvDim + c] = f2bu(s);
}

// ---- K4: per-(b,chunk,head) end-of-chunk state
__global__ void chunk_state_kernel(const unsigned short* __restrict__ xbc_act,
                                   const float* __restrict__ dtbuf,
                                   const float* __restrict__ A_log,
                                   unsigned short* __restrict__ states,
                                   float* __restrict__ asum) {
  const int id = blockIdx.x;
  const int h = id & 31;
  const int c = (id >> 5) & (kNC - 1);
  const int b = id >> 11;
  const int tid = threadIdx.x;
  __shared__ float s_dt[kCS];
  __shared__ float s_acum[kCS];
  __shared__ float s_xdd[kCS * kHP];
  __shared__ unsigned short s_B[kCS * kDS];
  const int l0 = b * kL + c * kCS;
  if (tid < kCS) s_dt[tid] = dtbuf[(size_t)(l0 + tid) * kNH + h];
  __syncthreads();
  if (tid == 0) {
    float A = -expf(A_log[h]);
    float run = 0.f;
    for (int s = 0; s < kCS; s++) { run += A * s_dt[s]; s_acum[s] = run; }
    asum[id] = run;
  }
  __syncthreads();
  const float total = s_acum[kCS - 1];
  for (int e = tid; e < kCS * kDS; e += 256) {
    int s = e >> 7, n = e & 127;
    s_B[e] = xbc_act[(size_t)(l0 + s) * kConvDim + kDI + n];
  }
  for (int e = tid; e < kCS * kHP; e += 256) {
    int s = e >> 6, p = e & 63;
    float xv = bu2f(xbc_act[(size_t)(l0 + s) * kConvDim + h * kHP + p]);
    s_xdd[e] = xv * s_dt[s] * expf(total - s_acum[s]);
  }
  __syncthreads();
  const int p = tid >> 2;
  const int n0 = (tid & 3) * 32;
  float acc[32];
#pragma unroll
  for (int j = 0; j < 32; j++) acc[j] = 0.f;
  for (int s = 0; s < kCS; s++) {
    float xv = s_xdd[s * kHP + p];
#pragma unroll
    for (int j = 0; j < 32; j++) acc[j] += xv * bu2f(s_B[s * kDS + n0 + j]);
  }
  size_t base = ((size_t)id * kHP + p) * kDS + n0;
#pragma unroll
  for (int j = 0; j < 32; j++) states[base + j] = f2bu(acc[j]);
}

// ---- K5: sequential inter-chunk scan (in place: states[c] <- states_in[c])
__global__ void scan_kernel(unsigned short* __restrict__ states,
                            const float* __restrict__ asum) {
  const int blk = blockIdx.x;
  const int seg = blk & 31;
  const int bh = blk >> 5;
  const int h = bh & 31, b = bh >> 5;
  const int e = seg * 256 + threadIdx.x;
  float carry = 0.f;
  for (int c = 0; c < kNC; c++) {
    const int id = (b * kNC + c) * kNH + h;
    size_t addr = (size_t)id * (kHP * kDS) + e;
    float decay = expf(asum[id]);
    float tmp = bu2f(states[addr]);
    states[addr] = f2bu(carry);
    carry = carry * decay + tmp;
  }
}

// ---- K6: intra-chunk Y + carried state + SiLU(z) gate (bf16 out)
__global__ void y_kernel(const unsigned short* __restrict__ xbc_act,
                         const unsigned short* __restrict__ zxbcdt,
                         const unsigned short* __restrict__ states_in,
                         const float* __restrict__ dtbuf,
                         const float* __restrict__ A_log,
                         unsigned short* __restrict__ ybuf) {
  const int id = blockIdx.x;
  const int h = id & 31;
  const int c = (id >> 5) & (kNC - 1);
  const int b = id >> 11;
  const int tid = threadIdx.x;
  __shared__ unsigned short s_B[kCS * kDSP];
  __shared__ unsigned short s_C[kCS * kDSP];
  __shared__ unsigned short s_xd[kCS * kHP];
  __shared__ float s_W[kCS * kCS];
  __shared__ float s_dt[kCS];
  __shared__ float s_acum[kCS];
  const int l0 = b * kL + c * kCS;
  if (tid < kCS) s_dt[tid] = dtbuf[(size_t)(l0 + tid) * kNH + h];
  __syncthreads();
  if (tid == 0) {
    float A = -expf(A_log[h]);
    float run = 0.f;
    for (int s = 0; s < kCS; s++) { run += A * s_dt[s]; s_acum[s] = run; }
  }
  __syncthreads();
  for (int e = tid; e < kCS * kDS; e += 256) {
    int s = e >> 7, n = e & 127;
    size_t rb = (size_t)(l0 + s) * kConvDim;
    s_B[s * kDSP + n] = xbc_act[rb + kDI + n];
    s_C[s * kDSP + n] = xbc_act[rb + kDI + kDS + n];
  }
  for (int e = tid; e < kCS * kHP; e += 256) {
    int s = e >> 6, p = e & 63;
    float xv = bu2f(xbc_act[(size_t)(l0 + s) * kConvDim + h * kHP + p]);
    s_xd[e] = f2bu(xv * s_dt[s]);
  }
  __syncthreads();
  for (int e = tid; e < kCS * kCS; e += 256) {
    int l = e >> 6, s = e & 63;
    float w = 0.f;
    if (s <= l) {
      float dot = 0.f;
      for (int n = 0; n < kDS; n++)
        dot += bu2f(s_C[l * kDSP + n]) * bu2f(s_B[s * kDSP + n]);
      w = dot * expf(s_acum[l] - s_acum[s]);
    }
    s_W[e] = w;
  }
  __syncthreads();
  for (int e = tid; e < kHP * kDS; e += 256) {
    int p = e >> 7, n = e & 127;
    s_B[p * kDSP + n] = states_in[(size_t)id * (kHP * kDS) + e];
  }
  __syncthreads();
  for (int e = tid; e < kCS * kHP; e += 256) {
    int l = e >> 6, p = e & 63;
    float acc = 0.f;
    for (int s = 0; s <= l; s++)
      acc += s_W[l * kCS + s] * bu2f(s_xd[s * kHP + p]);
    float off = 0.f;
    for (int n = 0; n < kDS; n++)
      off += bu2f(s_C[l * kDSP + n]) * bu2f(s_B[p * kDSP + n]);
    acc += off * expf(s_acum[l]);
    float z = bu2f(zxbcdt[(size_t)(l0 + l) * kDProj + h * kHP + p]);
    float g = z / (1.f + expf(-z));
    ybuf[(size_t)(l0 + l) * kDI + h * kHP + p] = f2bu(acc * g);
  }
}

// ---- K7: LayerNorm over DI, bf16, in place
__global__ void ln_kernel(unsigned short* __restrict__ ybuf,
                          const float* __restrict__ norm_w,
                          const float* __restrict__ norm_b) {
  const int row = blockIdx.x;
  unsigned short* y = ybuf + (size_t)row * kDI;
  float s = 0.f, ss = 0.f;
  for (int i = threadIdx.x; i < kDI; i += 256) {
    float v = bu2f(y[i]);
    s += v; ss += v * v;
  }
#pragma unroll
  for (int off = 32; off > 0; off >>= 1) {
    s += __shfl_down(s, off);
    ss += __shfl_down(ss, off);
  }
  __shared__ float red[8];
  int lane = threadIdx.x & 63, wv = threadIdx.x >> 6;
  if (lane == 0) { red[wv] = s; red[4 + wv] = ss; }
  __syncthreads();
  if (threadIdx.x == 0) {
    float S = red[0] + red[1] + red[2] + red[3];
    float SS = red[4] + red[5] + red[6] + red[7];
    float mu = S / kDI;
    float var = SS / kDI - mu * mu;
    red[0] = mu;
    red[1] = rsqrtf(var + kEps);
  }
  __syncthreads();
  float mu = red[0], rstd = red[1];
  for (int i = threadIdx.x; i < kDI; i += 256)
    y[i] = f2bu((bu2f(y[i]) - mu) * rstd * norm_w[i] + norm_b[i]);
}

}  // namespace

extern "C" void kernel_launch(void* const* d_in, const int* in_sizes, int n_in,
                              void* d_out, int out_size, void* d_ws, size_t ws_size,
                              hipStream_t stream) {
  const float* u       = (const float*)d_in[0];
  const float* W_in    = (const float*)d_in[1];
  const float* conv_w  = (const float*)d_in[2];
  const float* conv_b  = (const float*)d_in[3];
  const float* dt_bias = (const float*)d_in[4];
  const float* A_log   = (const float*)d_in[5];
  const float* norm_w  = (const float*)d_in[6];
  const float* norm_b  = (const float*)d_in[7];
  const float* W_out   = (const float*)d_in[8];
  float* out = (float*)d_out;

  char* ws = (char*)d_ws;
  size_t off = 0;
  auto alloc = [&](size_t bytes) {
    void* p = ws + off;
    off += (bytes + 255) & ~(size_t)255;
    return p;
  };
  // Private (non-aliased) buffers, ~230 MiB total.
  unsigned short* zxbcdt = (unsigned short*)alloc((size_t)kRows * kDProj * 2);        // 71.8 MB
  unsigned short* xbc    = (unsigned short*)alloc((size_t)kRows * kConvDim * 2);      // 37.7 MB
  float* dtb             = (float*)alloc((size_t)kRows * kNH * 4);                    //  1.0 MB
  float* asum            = (float*)alloc((size_t)kB * kNC * kNH * 4);                 // 16 KB
  unsigned short* A1     = (unsigned short*)alloc((size_t)kRows * 1024 * 2);          // 16.8 MB
  unsigned short* Bt1    = (unsigned short*)alloc((size_t)kDProjP * 1024 * 2);        //  9.2 MB
  unsigned short* states = (unsigned short*)alloc((size_t)kB * kNC * kNH * kHP * kDS * 2); // 67.1 MB
  unsigned short* Bt2    = (unsigned short*)alloc((size_t)1024 * kDI * 2);            //  4.2 MB
  unsigned short* ybuf   = (unsigned short*)alloc((size_t)kRows * kDI * 2);           // 33.6 MB
  (void)ws_size; (void)in_sizes; (void)n_in; (void)out_size;

  // C0: u -> bf16
  cast_kernel<<<(kRows * 1024 / 4 + 255) / 256, 256, 0, stream>>>(
      (const float4*)u, (ushort4*)A1, kRows * 1024 / 4);
  // C1: W_in [1024][4384] -> Bt1 [4480][1024]
  transpose_cast<<<dim3(kDProjP / 32, 1024 / 32), 256, 0, stream>>>(W_in, Bt1, 1024, kDProj, kDProjP);
  // K1: zxbcdt = u @ W_in
  gemm_bt<unsigned short><<<dim3(kDProjP / 128, kRows / 128), 256, 0, stream>>>(
      A1, Bt1, zxbcdt, kRows, kDProj, 1024);
  // K2: dt
  dt_kernel<<<(kRows * kNH + 255) / 256, 256, 0, stream>>>(zxbcdt, dt_bias, dtb);
  // K3: conv + silu
  conv_silu_kernel<<<dim3((kConvDim + 255) / 256, kRows), 256, 0, stream>>>(
      zxbcdt, conv_w, conv_b, xbc);
  // K4: per-chunk states
  chunk_state_kernel<<<kB * kNC * kNH, 256, 0, stream>>>(xbc, dtb, A_log, states, asum);
  // K5: inter-chunk scan
  scan_kernel<<<kB * kNH * 32, 256, 0, stream>>>(states, asum);
  // K6: Y + gate (bf16 out)
  y_kernel<<<kB * kNC * kNH, 256, 0, stream>>>(xbc, zxbcdt, states, dtb, A_log, ybuf);
  // C2: W_out [2048][1024] -> Bt2 [1024][2048]
  transpose_cast<<<dim3(1024 / 32, 2048 / 32), 256, 0, stream>>>(W_out, Bt2, 2048, 1024, 1024);
  // K7: LayerNorm in place
  ln_kernel<<<kRows, 256, 0, stream>>>(ybuf, norm_w, norm_b);
  // K8: out = y_norm @ W_out
  gemm_bt<float><<<dim3(1024 / 128, kRows / 128), 256, 0, stream>>>(
      ybuf, Bt2, out, kRows, 1024, 2048);
}

// Round 4
// 517.288 us; speedup vs baseline: 5.7890x; 2.1785x over previous
//
#include <hip/hip_runtime.h>
#include <hip/hip_bf16.h>
#include <math.h>

// ---------------------------------------------------------------------------
// Mamba2 forward, MI355X. Round 4: SSD middle (y_kernel, chunk_state) moved
// to MFMA. Per (b,chunk,head) block:
//   chunk_state: S[p][n] = MFMA(xddT[p][s], BT[n][s])           (K=64)
//   y_kernel:    G = MFMA(C[l][n], B[s][n])                     (K=128)
//                W = mask(G)*exp(acum_l-acum_s) -> bf16 LDS (C/D->A round-trip)
//                Yd = MFMA(W[l][s], xdT[p][s])                  (K=64)
//                Yoff = MFMA(C[l][n], Sin[p][n])                (K=128)
//                y = (Yd + exp(acum_l)*Yoff) * silu(z)
// GEMMs (K1/K8) unchanged from round 3 (m97 structure, hardened vmcnt drain).
// ---------------------------------------------------------------------------

namespace {

constexpr int kB   = 2;
constexpr int kL   = 4096;
constexpr int kDI  = 2048;
constexpr int kDS  = 128;
constexpr int kNH  = 32;
constexpr int kHP  = 64;
constexpr int kDC  = 4;
constexpr int kCS  = 64;
constexpr int kNC  = kL / kCS;
constexpr int kDProj   = 2 * kDI + 2 * kDS + kNH;  // 4384
constexpr int kDProjP  = 4480;                     // 35*128
constexpr int kConvDim = kDI + 2 * kDS;            // 2304
constexpr int kRows = kB * kL;                     // 8192
constexpr float kEps = 1e-5f;
constexpr int kTS = 136;   // LDS stride for [64][128] tiles (16B-aligned rows)
constexpr int kWS = 72;    // LDS stride for [64][64] tiles

typedef __bf16 bf16x8 __attribute__((ext_vector_type(8)));
typedef float f32x4 __attribute__((ext_vector_type(4)));
typedef unsigned short ushort8 __attribute__((ext_vector_type(8)));

__device__ inline float bu2f(unsigned short u) {
  union { unsigned int i; float f; } x; x.i = ((unsigned int)u) << 16; return x.f;
}
__device__ inline unsigned short f2bu(float f) {
  __hip_bfloat16 h = __float2bfloat16(f);
  return *reinterpret_cast<unsigned short*>(&h);
}

__device__ inline void store_out(float* C, size_t i, float v) { C[i] = v; }
__device__ inline void store_out(unsigned short* C, size_t i, float v) { C[i] = f2bu(v); }

__device__ inline void gld_lds16(const unsigned short* g, unsigned short* l) {
  __builtin_amdgcn_global_load_lds(
      (const __attribute__((address_space(1))) unsigned int*)g,
      (__attribute__((address_space(3))) unsigned int*)l, 16, 0, 0);
}

// ---- cast fp32 -> bf16
__global__ void cast_kernel(const float4* __restrict__ in, ushort4* __restrict__ out, int n4) {
  int i = blockIdx.x * 256 + threadIdx.x;
  if (i >= n4) return;
  float4 v = in[i];
  ushort4 o;
  o.x = f2bu(v.x); o.y = f2bu(v.y); o.z = f2bu(v.z); o.w = f2bu(v.w);
  out[i] = o;
}

// ---- transpose + cast: in[R][C] fp32 -> out[Cpad][R] bf16
__global__ void transpose_cast(const float* __restrict__ in, unsigned short* __restrict__ out,
                               int R, int C, int Cpad) {
  __shared__ float t[32][33];
  const int c0 = blockIdx.x * 32;
  const int r0 = blockIdx.y * 32;
  const int tx = threadIdx.x & 31, ty = threadIdx.x >> 5;
  for (int rr = ty; rr < 32; rr += 8) {
    int c = c0 + tx;
    t[rr][tx] = (c < C) ? in[(size_t)(r0 + rr) * C + c] : 0.f;
  }
  __syncthreads();
  for (int cc = ty; cc < 32; cc += 8) {
    int orow = c0 + cc;
    out[(size_t)orow * R + r0 + tx] = f2bu(t[tx][cc]);
  }
}

// ---- MFMA GEMM: C[M][N] = A[M][K] * Bt[N][K]^T, bf16 in, 128x128 tile.
template <typename OutT>
__global__ __launch_bounds__(256) void gemm_bt(const unsigned short* __restrict__ A,
                                               const unsigned short* __restrict__ Bt,
                                               OutT* __restrict__ C, int M, int N, int K) {
  __shared__ __align__(16) unsigned short As[128 * 32];
  __shared__ __align__(16) unsigned short Bs[128 * 32];
  const int tid = threadIdx.x;
  const int wave = tid >> 6, lane = tid & 63;
  const int m0 = blockIdx.y * 128, n0 = blockIdx.x * 128;
  const int wr = (wave >> 1) * 64, wc = (wave & 1) * 64;
  const int st_row = lane >> 2;
  const int st_col = (lane & 3) * 8;
  const unsigned short* pA[2];
  const unsigned short* pB[2];
  unsigned short* lA[2];
  unsigned short* lB[2];
#pragma unroll
  for (int r = 0; r < 2; r++) {
    int q = wave * 2 + r;
    pA[r] = A + (size_t)(m0 + q * 16 + st_row) * K + st_col;
    pB[r] = Bt + (size_t)(n0 + q * 16 + st_row) * K + st_col;
    lA[r] = &As[q * 512];
    lB[r] = &Bs[q * 512];
  }
  const int frag_row = lane & 15;
  const int frag_k = (lane >> 4) * 8;
  f32x4 acc[4][4] = {};
  for (int k0 = 0; k0 < K; k0 += 32) {
#pragma unroll
    for (int r = 0; r < 2; r++) {
      gld_lds16(pA[r] + k0, lA[r]);
      gld_lds16(pB[r] + k0, lB[r]);
    }
    asm volatile("s_waitcnt vmcnt(0)" ::: "memory");
    __syncthreads();
    bf16x8 af[4], bfr[4];
#pragma unroll
    for (int i = 0; i < 4; i++)
      af[i] = *(const bf16x8*)&As[(wr + i * 16 + frag_row) * 32 + frag_k];
#pragma unroll
    for (int j = 0; j < 4; j++)
      bfr[j] = *(const bf16x8*)&Bs[(wc + j * 16 + frag_row) * 32 + frag_k];
#pragma unroll
    for (int i = 0; i < 4; i++)
#pragma unroll
      for (int j = 0; j < 4; j++)
        acc[i][j] = __builtin_amdgcn_mfma_f32_16x16x32_bf16(af[i], bfr[j], acc[i][j], 0, 0, 0);
    __syncthreads();
  }
  const int crow = (lane >> 4) * 4;
  const int ccol = lane & 15;
#pragma unroll
  for (int i = 0; i < 4; i++) {
#pragma unroll
    for (int j = 0; j < 4; j++) {
      int n = n0 + wc + j * 16 + ccol;
      if (n < N) {
#pragma unroll
        for (int r = 0; r < 4; r++) {
          int m = m0 + wr + i * 16 + crow + r;
          store_out(C, (size_t)m * N + n, acc[i][j][r]);
        }
      }
    }
  }
}

// ---- K2: dt = softplus(dt_raw + dt_bias)
__global__ void dt_kernel(const unsigned short* __restrict__ zxbcdt,
                          const float* __restrict__ dt_bias,
                          float* __restrict__ dtbuf) {
  int idx = blockIdx.x * 256 + threadIdx.x;
  if (idx >= kRows * kNH) return;
  int row = idx >> 5, h = idx & 31;
  float x = bu2f(zxbcdt[(size_t)row * kDProj + (kDProj - kNH) + h]) + dt_bias[h];
  dtbuf[idx] = (x > 15.f) ? x : log1pf(expf(x));
}

// ---- K3: causal depthwise conv (k=4) + SiLU
__global__ void conv_silu_kernel(const unsigned short* __restrict__ zxbcdt,
                                 const float* __restrict__ conv_w,
                                 const float* __restrict__ conv_b,
                                 unsigned short* __restrict__ xbc_act) {
  int c = blockIdx.x * 256 + threadIdx.x;
  int row = blockIdx.y;
  if (c >= kConvDim) return;
  int b = row >> 12, l = row & (kL - 1);
  float acc = conv_b[c];
#pragma unroll
  for (int i = 0; i < kDC; i++) {
    int li = l - (kDC - 1) + i;
    if (li >= 0)
      acc += bu2f(zxbcdt[(size_t)(b * kL + li) * kDProj + kDI + c]) * conv_w[c * kDC + i];
  }
  float s = acc / (1.f + expf(-acc));
  xbc_act[(size_t)row * kConvDim + c] = f2bu(s);
}

// ---- K4: per-(b,chunk,head) end-of-chunk state via MFMA
__global__ __launch_bounds__(256) void chunk_state_kernel(
    const unsigned short* __restrict__ xbc_act,
    const float* __restrict__ dtbuf,
    const float* __restrict__ A_log,
    unsigned short* __restrict__ states,
    float* __restrict__ asum) {
  const int id = blockIdx.x;
  const int h = id & 31;
  const int c = (id >> 5) & (kNC - 1);
  const int b = id >> 11;
  const int tid = threadIdx.x;
  const int wave = tid >> 6, lane = tid & 63;
  __shared__ __align__(16) unsigned short sBT[kDS * kWS];   // B^T [n][s]
  __shared__ __align__(16) unsigned short sxd[kCS * kWS];   // xdd^T [p][s]
  __shared__ float s_dt[kCS];
  __shared__ float s_acum[kCS];
  const int l0 = b * kL + c * kCS;
  if (tid < kCS) s_dt[tid] = dtbuf[(size_t)(l0 + tid) * kNH + h];
  __syncthreads();
  if (tid == 0) {
    float A = -expf(A_log[h]);
    float run = 0.f;
    for (int s = 0; s < kCS; s++) { run += A * s_dt[s]; s_acum[s] = run; }
    asum[id] = run;
  }
  __syncthreads();
  const float total = s_acum[kCS - 1];
  // stage B transposed: [s][n] global -> [n][s] LDS
  for (int e = tid; e < kCS * kDS; e += 256) {
    int s = e >> 7, n = e & 127;
    sBT[n * kWS + s] = xbc_act[(size_t)(l0 + s) * kConvDim + kDI + n];
  }
  // stage xdd transposed: [s][p] -> [p][s], xdd = x*dt*exp(total-acum)
  for (int e = tid; e < kCS * kHP; e += 256) {
    int s = e >> 6, p = e & 63;
    float xv = bu2f(xbc_act[(size_t)(l0 + s) * kConvDim + h * kHP + p]);
    sxd[p * kWS + s] = f2bu(xv * s_dt[s] * expf(total - s_acum[s]));
  }
  __syncthreads();
  const int arow = wave * 16 + (lane & 15);
  const int fk = (lane >> 4) * 8;
  f32x4 acc[8] = {};
#pragma unroll
  for (int kk = 0; kk < 2; kk++) {
    bf16x8 a = *(const bf16x8*)&sxd[arow * kWS + kk * 32 + fk];
#pragma unroll
    for (int j = 0; j < 8; j++) {
      bf16x8 bb = *(const bf16x8*)&sBT[(j * 16 + (lane & 15)) * kWS + kk * 32 + fk];
      acc[j] = __builtin_amdgcn_mfma_f32_16x16x32_bf16(a, bb, acc[j], 0, 0, 0);
    }
  }
  const int prow = wave * 16 + (lane >> 4) * 4;
  const int ncol = lane & 15;
  size_t base = (size_t)id * (kHP * kDS);
#pragma unroll
  for (int j = 0; j < 8; j++)
#pragma unroll
    for (int r = 0; r < 4; r++)
      states[base + (size_t)(prow + r) * kDS + j * 16 + ncol] = f2bu(acc[j][r]);
}

// ---- K5: sequential inter-chunk scan (in place: states[c] <- states_in[c])
__global__ void scan_kernel(unsigned short* __restrict__ states,
                            const float* __restrict__ asum) {
  const int blk = blockIdx.x;
  const int seg = blk & 31;
  const int bh = blk >> 5;
  const int h = bh & 31, b = bh >> 5;
  const int e = seg * 256 + threadIdx.x;
  float carry = 0.f;
  for (int c = 0; c < kNC; c++) {
    const int id = (b * kNC + c) * kNH + h;
    size_t addr = (size_t)id * (kHP * kDS) + e;
    float decay = expf(asum[id]);
    float tmp = bu2f(states[addr]);
    states[addr] = f2bu(carry);
    carry = carry * decay + tmp;
  }
}

// ---- K6: intra-chunk Y + carried state + SiLU(z) gate, MFMA version
__global__ __launch_bounds__(256) void y_kernel(
    const unsigned short* __restrict__ xbc_act,
    const unsigned short* __restrict__ zxbcdt,
    const unsigned short* __restrict__ states_in,
    const float* __restrict__ dtbuf,
    const float* __restrict__ A_log,
    unsigned short* __restrict__ ybuf) {
  const int id = blockIdx.x;
  const int h = id & 31;
  const int c = (id >> 5) & (kNC - 1);
  const int b = id >> 11;
  const int tid = threadIdx.x;
  const int wave = tid >> 6, lane = tid & 63;
  __shared__ __align__(16) unsigned short sC[kCS * kTS];    // C [l][n]
  __shared__ __align__(16) unsigned short sB[kCS * kTS];    // B [s][n]; later Sin [p][n]
  __shared__ __align__(16) unsigned short sxd[kCS * kWS];   // xd^T [p][s]
  __shared__ __align__(16) unsigned short sW[kCS * kWS];    // W [l][s] bf16
  __shared__ float s_dt[kCS];
  __shared__ float s_acum[kCS];
  const int l0 = b * kL + c * kCS;
  if (tid < kCS) s_dt[tid] = dtbuf[(size_t)(l0 + tid) * kNH + h];
  __syncthreads();
  if (tid == 0) {
    float A = -expf(A_log[h]);
    float run = 0.f;
    for (int s = 0; s < kCS; s++) { run += A * s_dt[s]; s_acum[s] = run; }
  }
  __syncthreads();
  // stage C and B tiles (ushort8 vector copies, rows 16B-aligned)
  for (int e = tid; e < kCS * 16; e += 256) {
    int row = e >> 4, c8 = (e & 15) * 8;
    size_t rb = (size_t)(l0 + row) * kConvDim;
    *(ushort8*)&sB[row * kTS + c8] = *(const ushort8*)&xbc_act[rb + kDI + c8];
    *(ushort8*)&sC[row * kTS + c8] = *(const ushort8*)&xbc_act[rb + kDI + kDS + c8];
  }
  // stage xd transposed: [s][p] -> [p][s]
  for (int e = tid; e < kCS * kHP; e += 256) {
    int s = e >> 6, p = e & 63;
    float xv = bu2f(xbc_act[(size_t)(l0 + s) * kConvDim + h * kHP + p]);
    sxd[p * kWS + s] = f2bu(xv * s_dt[s]);
  }
  __syncthreads();
  const int arow = wave * 16 + (lane & 15);
  const int fk = (lane >> 4) * 8;
  // step 1: G[l][s] = C . B^T  (K=128)
  f32x4 accG[4] = {};
#pragma unroll
  for (int kk = 0; kk < 4; kk++) {
    bf16x8 a = *(const bf16x8*)&sC[arow * kTS + kk * 32 + fk];
#pragma unroll
    for (int j = 0; j < 4; j++) {
      bf16x8 bb = *(const bf16x8*)&sB[(j * 16 + (lane & 15)) * kTS + kk * 32 + fk];
      accG[j] = __builtin_amdgcn_mfma_f32_16x16x32_bf16(a, bb, accG[j], 0, 0, 0);
    }
  }
  // mask + decay -> W bf16 in LDS (C/D layout -> row-major, own strip only)
  const int lrow = wave * 16 + (lane >> 4) * 4;
#pragma unroll
  for (int j = 0; j < 4; j++) {
    int scol = j * 16 + (lane & 15);
    float as = s_acum[scol];
#pragma unroll
    for (int r = 0; r < 4; r++) {
      int l = lrow + r;
      float w = (scol <= l) ? accG[j][r] * expf(s_acum[l] - as) : 0.f;
      sW[l * kWS + scol] = f2bu(w);
    }
  }
  // step 2: Yd[l][p] = W . xd^T  (K=64; W rows are own-strip, wave-local DS order)
  f32x4 accY[4] = {};
#pragma unroll
  for (int kk = 0; kk < 2; kk++) {
    bf16x8 a = *(const bf16x8*)&sW[arow * kWS + kk * 32 + fk];
#pragma unroll
    for (int j = 0; j < 4; j++) {
      bf16x8 bb = *(const bf16x8*)&sxd[(j * 16 + (lane & 15)) * kWS + kk * 32 + fk];
      accY[j] = __builtin_amdgcn_mfma_f32_16x16x32_bf16(a, bb, accY[j], 0, 0, 0);
    }
  }
  __syncthreads();   // all waves done reading sB (step 1)
  // stage Sin[p][n] into sB space
  for (int e = tid; e < kCS * 16; e += 256) {
    int row = e >> 4, c8 = (e & 15) * 8;
    *(ushort8*)&sB[row * kTS + c8] =
        *(const ushort8*)&states_in[(size_t)id * (kHP * kDS) + row * kDS + c8];
  }
  __syncthreads();
  // step 3: Yoff[l][p] = C . Sin^T  (K=128)
  f32x4 accO[4] = {};
#pragma unroll
  for (int kk = 0; kk < 4; kk++) {
    bf16x8 a = *(const bf16x8*)&sC[arow * kTS + kk * 32 + fk];
#pragma unroll
    for (int j = 0; j < 4; j++) {
      bf16x8 bb = *(const bf16x8*)&sB[(j * 16 + (lane & 15)) * kTS + kk * 32 + fk];
      accO[j] = __builtin_amdgcn_mfma_f32_16x16x32_bf16(a, bb, accO[j], 0, 0, 0);
    }
  }
  // epilogue: y = (Yd + exp(acum_l)*Yoff) * silu(z)
#pragma unroll
  for (int r = 0; r < 4; r++) {
    int l = lrow + r;
    float el = expf(s_acum[l]);
    size_t zrow = (size_t)(l0 + l) * kDProj + h * kHP;
    size_t yrow = (size_t)(l0 + l) * kDI + h * kHP;
#pragma unroll
    for (int j = 0; j < 4; j++) {
      int p = j * 16 + (lane & 15);
      float yv = accY[j][r] + el * accO[j][r];
      float z = bu2f(zxbcdt[zrow + p]);
      yv *= z / (1.f + expf(-z));
      ybuf[yrow + p] = f2bu(yv);
    }
  }
}

// ---- K7: LayerNorm over DI, bf16, in place
__global__ void ln_kernel(unsigned short* __restrict__ ybuf,
                          const float* __restrict__ norm_w,
                          const float* __restrict__ norm_b) {
  const int row = blockIdx.x;
  unsigned short* y = ybuf + (size_t)row * kDI;
  float s = 0.f, ss = 0.f;
  for (int i = threadIdx.x; i < kDI; i += 256) {
    float v = bu2f(y[i]);
    s += v; ss += v * v;
  }
#pragma unroll
  for (int off = 32; off > 0; off >>= 1) {
    s += __shfl_down(s, off);
    ss += __shfl_down(ss, off);
  }
  __shared__ float red[8];
  int lane = threadIdx.x & 63, wv = threadIdx.x >> 6;
  if (lane == 0) { red[wv] = s; red[4 + wv] = ss; }
  __syncthreads();
  if (threadIdx.x == 0) {
    float S = red[0] + red[1] + red[2] + red[3];
    float SS = red[4] + red[5] + red[6] + red[7];
    float mu = S / kDI;
    float var = SS / kDI - mu * mu;
    red[0] = mu;
    red[1] = rsqrtf(var + kEps);
  }
  __syncthreads();
  float mu = red[0], rstd = red[1];
  for (int i = threadIdx.x; i < kDI; i += 256)
    y[i] = f2bu((bu2f(y[i]) - mu) * rstd * norm_w[i] + norm_b[i]);
}

}  // namespace

extern "C" void kernel_launch(void* const* d_in, const int* in_sizes, int n_in,
                              void* d_out, int out_size, void* d_ws, size_t ws_size,
                              hipStream_t stream) {
  const float* u       = (const float*)d_in[0];
  const float* W_in    = (const float*)d_in[1];
  const float* conv_w  = (const float*)d_in[2];
  const float* conv_b  = (const float*)d_in[3];
  const float* dt_bias = (const float*)d_in[4];
  const float* A_log   = (const float*)d_in[5];
  const float* norm_w  = (const float*)d_in[6];
  const float* norm_b  = (const float*)d_in[7];
  const float* W_out   = (const float*)d_in[8];
  float* out = (float*)d_out;

  char* ws = (char*)d_ws;
  size_t off = 0;
  auto alloc = [&](size_t bytes) {
    void* p = ws + off;
    off += (bytes + 255) & ~(size_t)255;
    return p;
  };
  unsigned short* zxbcdt = (unsigned short*)alloc((size_t)kRows * kDProj * 2);        // 71.8 MB
  unsigned short* xbc    = (unsigned short*)alloc((size_t)kRows * kConvDim * 2);      // 37.7 MB
  float* dtb             = (float*)alloc((size_t)kRows * kNH * 4);                    //  1.0 MB
  float* asum            = (float*)alloc((size_t)kB * kNC * kNH * 4);                 // 16 KB
  unsigned short* A1     = (unsigned short*)alloc((size_t)kRows * 1024 * 2);          // 16.8 MB
  unsigned short* Bt1    = (unsigned short*)alloc((size_t)kDProjP * 1024 * 2);        //  9.2 MB
  unsigned short* states = (unsigned short*)alloc((size_t)kB * kNC * kNH * kHP * kDS * 2); // 67.1 MB
  unsigned short* Bt2    = (unsigned short*)alloc((size_t)1024 * kDI * 2);            //  4.2 MB
  unsigned short* ybuf   = (unsigned short*)alloc((size_t)kRows * kDI * 2);           // 33.6 MB
  (void)ws_size; (void)in_sizes; (void)n_in; (void)out_size;

  cast_kernel<<<(kRows * 1024 / 4 + 255) / 256, 256, 0, stream>>>(
      (const float4*)u, (ushort4*)A1, kRows * 1024 / 4);
  transpose_cast<<<dim3(kDProjP / 32, 1024 / 32), 256, 0, stream>>>(W_in, Bt1, 1024, kDProj, kDProjP);
  gemm_bt<unsigned short><<<dim3(kDProjP / 128, kRows / 128), 256, 0, stream>>>(
      A1, Bt1, zxbcdt, kRows, kDProj, 1024);
  dt_kernel<<<(kRows * kNH + 255) / 256, 256, 0, stream>>>(zxbcdt, dt_bias, dtb);
  conv_silu_kernel<<<dim3((kConvDim + 255) / 256, kRows), 256, 0, stream>>>(
      zxbcdt, conv_w, conv_b, xbc);
  chunk_state_kernel<<<kB * kNC * kNH, 256, 0, stream>>>(xbc, dtb, A_log, states, asum);
  scan_kernel<<<kB * kNH * 32, 256, 0, stream>>>(states, asum);
  y_kernel<<<kB * kNC * kNH, 256, 0, stream>>>(xbc, zxbcdt, states, dtb, A_log, ybuf);
  transpose_cast<<<dim3(1024 / 32, 2048 / 32), 256, 0, stream>>>(W_out, Bt2, 2048, 1024, 1024);
  ln_kernel<<<kRows, 256, 0, stream>>>(ybuf, norm_w, norm_b);
  gemm_bt<float><<<dim3(1024 / 128, kRows / 128), 256, 0, stream>>>(
      ybuf, Bt2, out, kRows, 1024, 2048);
}

// Round 5
// 476.899 us; speedup vs baseline: 6.2793x; 1.0847x over previous
//
#include <hip/hip_runtime.h>
#include <hip/hip_bf16.h>
#include <math.h>

// ---------------------------------------------------------------------------
// Mamba2 forward, MI355X. Round 5:
//  - conv_silu: 8-row tiling (each input row read once, not 4x)
//  - y_kernel: 4 heads/block — B/C staging AND G=C.B^T computed once per block
//  - LayerNorm folded into K8 epilogue: out = rstd*(acc - mu*t1) + t2
//    (rowstat kernel for mu/rstd, colsum kernel for t1/t2, norm_w folded into Bt2)
//  - scan vectorized (ushort4)
// GEMMs keep the m97 structure (128x128 bf16 MFMA, global_load_lds, vmcnt drain).
// ---------------------------------------------------------------------------

namespace {

constexpr int kB   = 2;
constexpr int kL   = 4096;
constexpr int kDI  = 2048;
constexpr int kDS  = 128;
constexpr int kNH  = 32;
constexpr int kHP  = 64;
constexpr int kDC  = 4;
constexpr int kCS  = 64;
constexpr int kNC  = kL / kCS;
constexpr int kDProj   = 2 * kDI + 2 * kDS + kNH;  // 4384
constexpr int kDProjP  = 4480;                     // 35*128
constexpr int kConvDim = kDI + 2 * kDS;            // 2304
constexpr int kRows = kB * kL;                     // 8192
constexpr float kEps = 1e-5f;
constexpr int kTS = 136;   // LDS stride for [64][128] tiles
constexpr int kWS = 72;    // LDS stride for [64][64] tiles

typedef __bf16 bf16x8 __attribute__((ext_vector_type(8)));
typedef float f32x4 __attribute__((ext_vector_type(4)));
typedef unsigned short ushort8 __attribute__((ext_vector_type(8)));

__device__ inline float bu2f(unsigned short u) {
  union { unsigned int i; float f; } x; x.i = ((unsigned int)u) << 16; return x.f;
}
__device__ inline unsigned short f2bu(float f) {
  __hip_bfloat16 h = __float2bfloat16(f);
  return *reinterpret_cast<unsigned short*>(&h);
}

__device__ inline void store_out(float* C, size_t i, float v) { C[i] = v; }
__device__ inline void store_out(unsigned short* C, size_t i, float v) { C[i] = f2bu(v); }

__device__ inline void gld_lds16(const unsigned short* g, unsigned short* l) {
  __builtin_amdgcn_global_load_lds(
      (const __attribute__((address_space(1))) unsigned int*)g,
      (__attribute__((address_space(3))) unsigned int*)l, 16, 0, 0);
}

// ---- cast fp32 -> bf16
__global__ void cast_kernel(const float4* __restrict__ in, ushort4* __restrict__ out, int n4) {
  int i = blockIdx.x * 256 + threadIdx.x;
  if (i >= n4) return;
  float4 v = in[i];
  ushort4 o;
  o.x = f2bu(v.x); o.y = f2bu(v.y); o.z = f2bu(v.z); o.w = f2bu(v.w);
  out[i] = o;
}

// ---- transpose + cast (+optional per-row scale): in[R][C] fp32 -> out[Cpad][R] bf16
__global__ void transpose_cast(const float* __restrict__ in, unsigned short* __restrict__ out,
                               int R, int C, const float* __restrict__ scale) {
  __shared__ float t[32][33];
  const int c0 = blockIdx.x * 32;
  const int r0 = blockIdx.y * 32;
  const int tx = threadIdx.x & 31, ty = threadIdx.x >> 5;
  for (int rr = ty; rr < 32; rr += 8) {
    int c = c0 + tx;
    float v = (c < C) ? in[(size_t)(r0 + rr) * C + c] : 0.f;
    if (scale) v *= scale[r0 + rr];
    t[rr][tx] = v;
  }
  __syncthreads();
  for (int cc = ty; cc < 32; cc += 8) {
    int orow = c0 + cc;
    out[(size_t)orow * R + r0 + tx] = f2bu(t[tx][cc]);
  }
}

// ---- t1[n] = sum_k w[k]*W2[k][n], t2[n] = sum_k b[k]*W2[k][n]  (W2: [2048][1024])
__global__ void colsum_kernel(const float* __restrict__ W2, const float* __restrict__ wv,
                              const float* __restrict__ bv,
                              float* __restrict__ t1, float* __restrict__ t2) {
  __shared__ float p1[4][64], p2[4][64];
  const int nl = threadIdx.x & 63;
  const int ks = threadIdx.x >> 6;
  const int n = blockIdx.x * 64 + nl;
  float s1 = 0.f, s2 = 0.f;
  for (int k = ks * 512; k < ks * 512 + 512; k++) {
    float v = W2[(size_t)k * 1024 + n];
    s1 += wv[k] * v;
    s2 += bv[k] * v;
  }
  p1[ks][nl] = s1; p2[ks][nl] = s2;
  __syncthreads();
  if (threadIdx.x < 64) {
    t1[blockIdx.x * 64 + threadIdx.x] =
        p1[0][threadIdx.x] + p1[1][threadIdx.x] + p1[2][threadIdx.x] + p1[3][threadIdx.x];
    t2[blockIdx.x * 64 + threadIdx.x] =
        p2[0][threadIdx.x] + p2[1][threadIdx.x] + p2[2][threadIdx.x] + p2[3][threadIdx.x];
  }
}

// ---- MFMA GEMM: C[M][N] = A[M][K] * Bt[N][K]^T, bf16 in, 128x128 tile.
// FOLD: apply out = rstd[m]*(acc - mu[m]*t1[n]) + t2[n] (LayerNorm folded).
template <typename OutT, bool FOLD>
__global__ __launch_bounds__(256) void gemm_bt(const unsigned short* __restrict__ A,
                                               const unsigned short* __restrict__ Bt,
                                               OutT* __restrict__ C, int M, int N, int K,
                                               const float* __restrict__ mu,
                                               const float* __restrict__ rstd,
                                               const float* __restrict__ t1,
                                               const float* __restrict__ t2) {
  __shared__ __align__(16) unsigned short As[128 * 32];
  __shared__ __align__(16) unsigned short Bs[128 * 32];
  const int tid = threadIdx.x;
  const int wave = tid >> 6, lane = tid & 63;
  const int m0 = blockIdx.y * 128, n0 = blockIdx.x * 128;
  const int wr = (wave >> 1) * 64, wc = (wave & 1) * 64;
  const int st_row = lane >> 2;
  const int st_col = (lane & 3) * 8;
  const unsigned short* pA[2];
  const unsigned short* pB[2];
  unsigned short* lA[2];
  unsigned short* lB[2];
#pragma unroll
  for (int r = 0; r < 2; r++) {
    int q = wave * 2 + r;
    pA[r] = A + (size_t)(m0 + q * 16 + st_row) * K + st_col;
    pB[r] = Bt + (size_t)(n0 + q * 16 + st_row) * K + st_col;
    lA[r] = &As[q * 512];
    lB[r] = &Bs[q * 512];
  }
  const int frag_row = lane & 15;
  const int frag_k = (lane >> 4) * 8;
  f32x4 acc[4][4] = {};
  for (int k0 = 0; k0 < K; k0 += 32) {
#pragma unroll
    for (int r = 0; r < 2; r++) {
      gld_lds16(pA[r] + k0, lA[r]);
      gld_lds16(pB[r] + k0, lB[r]);
    }
    asm volatile("s_waitcnt vmcnt(0)" ::: "memory");
    __syncthreads();
    bf16x8 af[4], bfr[4];
#pragma unroll
    for (int i = 0; i < 4; i++)
      af[i] = *(const bf16x8*)&As[(wr + i * 16 + frag_row) * 32 + frag_k];
#pragma unroll
    for (int j = 0; j < 4; j++)
      bfr[j] = *(const bf16x8*)&Bs[(wc + j * 16 + frag_row) * 32 + frag_k];
#pragma unroll
    for (int i = 0; i < 4; i++)
#pragma unroll
      for (int j = 0; j < 4; j++)
        acc[i][j] = __builtin_amdgcn_mfma_f32_16x16x32_bf16(af[i], bfr[j], acc[i][j], 0, 0, 0);
    __syncthreads();
  }
  const int crow = (lane >> 4) * 4;
  const int ccol = lane & 15;
#pragma unroll
  for (int i = 0; i < 4; i++) {
#pragma unroll
    for (int j = 0; j < 4; j++) {
      int n = n0 + wc + j * 16 + ccol;
      if (n < N) {
        float c1 = FOLD ? t1[n] : 0.f;
        float c2 = FOLD ? t2[n] : 0.f;
#pragma unroll
        for (int r = 0; r < 4; r++) {
          int m = m0 + wr + i * 16 + crow + r;
          float v = acc[i][j][r];
          if (FOLD) v = rstd[m] * (v - mu[m] * c1) + c2;
          store_out(C, (size_t)m * N + n, v);
        }
      }
    }
  }
}

// ---- K2: dt = softplus(dt_raw + dt_bias)
__global__ void dt_kernel(const unsigned short* __restrict__ zxbcdt,
                          const float* __restrict__ dt_bias,
                          float* __restrict__ dtbuf) {
  int idx = blockIdx.x * 256 + threadIdx.x;
  if (idx >= kRows * kNH) return;
  int row = idx >> 5, h = idx & 31;
  float x = bu2f(zxbcdt[(size_t)row * kDProj + (kDProj - kNH) + h]) + dt_bias[h];
  dtbuf[idx] = (x > 15.f) ? x : log1pf(expf(x));
}

// ---- K3: causal depthwise conv (k=4) + SiLU, 8 rows/thread
__global__ void conv_silu_kernel(const unsigned short* __restrict__ zxbcdt,
                                 const float* __restrict__ conv_w,
                                 const float* __restrict__ conv_b,
                                 unsigned short* __restrict__ xbc_act) {
  int c = blockIdx.x * 256 + threadIdx.x;
  if (c >= kConvDim) return;
  const int r0 = blockIdx.y * 8;           // row-group of 8 (never crosses batch)
  const int l0 = r0 & (kL - 1);
  const float w0 = conv_w[c * 4], w1 = conv_w[c * 4 + 1];
  const float w2 = conv_w[c * 4 + 2], w3 = conv_w[c * 4 + 3];
  const float bias = conv_b[c];
  float v[11];
#pragma unroll
  for (int i = 0; i < 11; i++) {
    int l = l0 - 3 + i;
    v[i] = (l >= 0) ? bu2f(zxbcdt[(size_t)(r0 - 3 + i) * kDProj + kDI + c]) : 0.f;
  }
#pragma unroll
  for (int j = 0; j < 8; j++) {
    float a = bias + v[j] * w0 + v[j + 1] * w1 + v[j + 2] * w2 + v[j + 3] * w3;
    xbc_act[(size_t)(r0 + j) * kConvDim + c] = f2bu(a / (1.f + expf(-a)));
  }
}

// ---- K4: per-(b,chunk,head) end-of-chunk state via MFMA
__global__ __launch_bounds__(256) void chunk_state_kernel(
    const unsigned short* __restrict__ xbc_act,
    const float* __restrict__ dtbuf,
    const float* __restrict__ A_log,
    unsigned short* __restrict__ states,
    float* __restrict__ asum) {
  const int id = blockIdx.x;
  const int h = id & 31;
  const int c = (id >> 5) & (kNC - 1);
  const int b = id >> 11;
  const int tid = threadIdx.x;
  const int wave = tid >> 6, lane = tid & 63;
  __shared__ __align__(16) unsigned short sBT[kDS * kWS];   // B^T [n][s]
  __shared__ __align__(16) unsigned short sxd[kCS * kWS];   // xdd^T [p][s]
  __shared__ float s_dt[kCS];
  __shared__ float s_acum[kCS];
  const int l0 = b * kL + c * kCS;
  if (tid < kCS) s_dt[tid] = dtbuf[(size_t)(l0 + tid) * kNH + h];
  __syncthreads();
  if (tid == 0) {
    float A = -expf(A_log[h]);
    float run = 0.f;
    for (int s = 0; s < kCS; s++) { run += A * s_dt[s]; s_acum[s] = run; }
    asum[id] = run;
  }
  __syncthreads();
  const float total = s_acum[kCS - 1];
  for (int e = tid; e < kCS * kDS; e += 256) {
    int s = e >> 7, n = e & 127;
    sBT[n * kWS + s] = xbc_act[(size_t)(l0 + s) * kConvDim + kDI + n];
  }
  for (int e = tid; e < kCS * kHP; e += 256) {
    int s = e >> 6, p = e & 63;
    float xv = bu2f(xbc_act[(size_t)(l0 + s) * kConvDim + h * kHP + p]);
    sxd[p * kWS + s] = f2bu(xv * s_dt[s] * expf(total - s_acum[s]));
  }
  __syncthreads();
  const int arow = wave * 16 + (lane & 15);
  const int fk = (lane >> 4) * 8;
  f32x4 acc[8] = {};
#pragma unroll
  for (int kk = 0; kk < 2; kk++) {
    bf16x8 a = *(const bf16x8*)&sxd[arow * kWS + kk * 32 + fk];
#pragma unroll
    for (int j = 0; j < 8; j++) {
      bf16x8 bb = *(const bf16x8*)&sBT[(j * 16 + (lane & 15)) * kWS + kk * 32 + fk];
      acc[j] = __builtin_amdgcn_mfma_f32_16x16x32_bf16(a, bb, acc[j], 0, 0, 0);
    }
  }
  const int prow = wave * 16 + (lane >> 4) * 4;
  const int ncol = lane & 15;
  size_t base = (size_t)id * (kHP * kDS);
#pragma unroll
  for (int j = 0; j < 8; j++)
#pragma unroll
    for (int r = 0; r < 4; r++)
      states[base + (size_t)(prow + r) * kDS + j * 16 + ncol] = f2bu(acc[j][r]);
}

// ---- K5: sequential inter-chunk scan, vectorized ushort4
__global__ void scan_kernel(unsigned short* __restrict__ states,
                            const float* __restrict__ asum) {
  const int blk = blockIdx.x;                // (b*NH + h)*8 + seg
  const int seg = blk & 7;
  const int bh = blk >> 3;
  const int h = bh & 31, b = bh >> 5;
  const int e4 = seg * 256 + threadIdx.x;    // ushort4 index within 2048
  float c0 = 0.f, c1 = 0.f, c2 = 0.f, c3 = 0.f;
  for (int c = 0; c < kNC; c++) {
    const int id = (b * kNC + c) * kNH + h;
    ushort4* p = (ushort4*)states + (size_t)id * 2048 + e4;
    float decay = expf(asum[id]);
    ushort4 t = *p;
    ushort4 o;
    o.x = f2bu(c0); o.y = f2bu(c1); o.z = f2bu(c2); o.w = f2bu(c3);
    *p = o;
    c0 = c0 * decay + bu2f(t.x);
    c1 = c1 * decay + bu2f(t.y);
    c2 = c2 * decay + bu2f(t.z);
    c3 = c3 * decay + bu2f(t.w);
  }
}

// ---- K6: intra-chunk Y, 4 heads per block (B/C staging + G computed once)
__global__ __launch_bounds__(256) void y_kernel(
    const unsigned short* __restrict__ xbc_act,
    const unsigned short* __restrict__ zxbcdt,
    const unsigned short* __restrict__ states_in,
    const float* __restrict__ dtbuf,
    const float* __restrict__ A_log,
    unsigned short* __restrict__ ybuf) {
  const int id = blockIdx.x;                 // (b*NC + c)*8 + hg
  const int hg = id & 7;
  const int c = (id >> 3) & (kNC - 1);
  const int b = id >> 9;
  const int tid = threadIdx.x;
  const int wave = tid >> 6, lane = tid & 63;
  __shared__ __align__(16) unsigned short sC[kCS * kTS];    // C [l][n]
  __shared__ __align__(16) unsigned short sB[kCS * kTS];    // B [s][n]; then Sin [p][n]
  __shared__ __align__(16) unsigned short sxd[kCS * kWS];   // xd^T [p][s]
  __shared__ __align__(16) unsigned short sW[kCS * kWS];    // W [l][s]
  __shared__ float s_dt[4][kCS];
  __shared__ float s_acum[4][kCS];
  const int l0 = b * kL + c * kCS;
  {
    int hh = tid >> 6, s = tid & 63;
    s_dt[hh][s] = dtbuf[(size_t)(l0 + s) * kNH + hg * 4 + hh];
  }
  __syncthreads();
  if (tid < 4) {
    float A = -expf(A_log[hg * 4 + tid]);
    float run = 0.f;
    for (int s = 0; s < kCS; s++) { run += A * s_dt[tid][s]; s_acum[tid][s] = run; }
  }
  // stage C and B tiles
  for (int e = tid; e < kCS * 16; e += 256) {
    int row = e >> 4, c8 = (e & 15) * 8;
    size_t rb = (size_t)(l0 + row) * kConvDim;
    *(ushort8*)&sB[row * kTS + c8] = *(const ushort8*)&xbc_act[rb + kDI + c8];
    *(ushort8*)&sC[row * kTS + c8] = *(const ushort8*)&xbc_act[rb + kDI + kDS + c8];
  }
  __syncthreads();
  const int arow = wave * 16 + (lane & 15);
  const int fk = (lane >> 4) * 8;
  // G[l][s] = C . B^T  (K=128) — head-independent, computed ONCE
  f32x4 accG[4] = {};
#pragma unroll
  for (int kk = 0; kk < 4; kk++) {
    bf16x8 a = *(const bf16x8*)&sC[arow * kTS + kk * 32 + fk];
#pragma unroll
    for (int j = 0; j < 4; j++) {
      bf16x8 bb = *(const bf16x8*)&sB[(j * 16 + (lane & 15)) * kTS + kk * 32 + fk];
      accG[j] = __builtin_amdgcn_mfma_f32_16x16x32_bf16(a, bb, accG[j], 0, 0, 0);
    }
  }
  const int lrow = wave * 16 + (lane >> 4) * 4;
  const size_t sbase = (size_t)((b * kNC + c) * kNH) * (kHP * kDS);
  for (int hh = 0; hh < 4; hh++) {
    const int h = hg * 4 + hh;
    __syncthreads();   // prior iteration (or G) done reading sB/sxd/sW
    // stage xd^T for this head
    for (int e = tid; e < kCS * kHP; e += 256) {
      int s = e >> 6, p = e & 63;
      float xv = bu2f(xbc_act[(size_t)(l0 + s) * kConvDim + h * kHP + p]);
      sxd[p * kWS + s] = f2bu(xv * s_dt[hh][s]);
    }
    // W = mask(G)*decay  (wave-local strip)
#pragma unroll
    for (int j = 0; j < 4; j++) {
      int scol = j * 16 + (lane & 15);
      float as = s_acum[hh][scol];
#pragma unroll
      for (int r = 0; r < 4; r++) {
        int l = lrow + r;
        float w = (scol <= l) ? accG[j][r] * expf(s_acum[hh][l] - as) : 0.f;
        sW[l * kWS + scol] = f2bu(w);
      }
    }
    // stage Sin[p][n] for this head into sB
    for (int e = tid; e < kCS * 16; e += 256) {
      int row = e >> 4, c8 = (e & 15) * 8;
      *(ushort8*)&sB[row * kTS + c8] =
          *(const ushort8*)&states_in[sbase + (size_t)h * (kHP * kDS) + row * kDS + c8];
    }
    __syncthreads();
    // Yd = W . xd^T  (K=64)
    f32x4 accY[4] = {};
#pragma unroll
    for (int kk = 0; kk < 2; kk++) {
      bf16x8 a = *(const bf16x8*)&sW[arow * kWS + kk * 32 + fk];
#pragma unroll
      for (int j = 0; j < 4; j++) {
        bf16x8 bb = *(const bf16x8*)&sxd[(j * 16 + (lane & 15)) * kWS + kk * 32 + fk];
        accY[j] = __builtin_amdgcn_mfma_f32_16x16x32_bf16(a, bb, accY[j], 0, 0, 0);
      }
    }
    // Yoff = C . Sin^T  (K=128)
    f32x4 accO[4] = {};
#pragma unroll
    for (int kk = 0; kk < 4; kk++) {
      bf16x8 a = *(const bf16x8*)&sC[arow * kTS + kk * 32 + fk];
#pragma unroll
      for (int j = 0; j < 4; j++) {
        bf16x8 bb = *(const bf16x8*)&sB[(j * 16 + (lane & 15)) * kTS + kk * 32 + fk];
        accO[j] = __builtin_amdgcn_mfma_f32_16x16x32_bf16(a, bb, accO[j], 0, 0, 0);
      }
    }
    // epilogue: y = (Yd + exp(acum_l)*Yoff) * silu(z)
#pragma unroll
    for (int r = 0; r < 4; r++) {
      int l = lrow + r;
      float el = expf(s_acum[hh][l]);
      size_t zrow = (size_t)(l0 + l) * kDProj + h * kHP;
      size_t yrow = (size_t)(l0 + l) * kDI + h * kHP;
#pragma unroll
      for (int j = 0; j < 4; j++) {
        int p = j * 16 + (lane & 15);
        float yv = accY[j][r] + el * accO[j][r];
        float z = bu2f(zxbcdt[zrow + p]);
        yv *= z / (1.f + expf(-z));
        ybuf[yrow + p] = f2bu(yv);
      }
    }
  }
}

// ---- K7: per-row mean / rstd of y (LN stats only; transform folded into K8)
__global__ void rowstat_kernel(const unsigned short* __restrict__ y,
                               float* __restrict__ mu, float* __restrict__ rstd) {
  const int row = blockIdx.x;
  const unsigned short* yr = y + (size_t)row * kDI;
  float s = 0.f, ss = 0.f;
  for (int i = threadIdx.x; i < kDI; i += 256) {
    float v = bu2f(yr[i]);
    s += v; ss += v * v;
  }
#pragma unroll
  for (int off = 32; off > 0; off >>= 1) {
    s += __shfl_down(s, off);
    ss += __shfl_down(ss, off);
  }
  __shared__ float red[8];
  int lane = threadIdx.x & 63, wv = threadIdx.x >> 6;
  if (lane == 0) { red[wv] = s; red[4 + wv] = ss; }
  __syncthreads();
  if (threadIdx.x == 0) {
    float S = red[0] + red[1] + red[2] + red[3];
    float SS = red[4] + red[5] + red[6] + red[7];
    float m = S / kDI;
    float var = SS / kDI - m * m;
    mu[row] = m;
    rstd[row] = rsqrtf(var + kEps);
  }
}

}  // namespace

extern "C" void kernel_launch(void* const* d_in, const int* in_sizes, int n_in,
                              void* d_out, int out_size, void* d_ws, size_t ws_size,
                              hipStream_t stream) {
  const float* u       = (const float*)d_in[0];
  const float* W_in    = (const float*)d_in[1];
  const float* conv_w  = (const float*)d_in[2];
  const float* conv_b  = (const float*)d_in[3];
  const float* dt_bias = (const float*)d_in[4];
  const float* A_log   = (const float*)d_in[5];
  const float* norm_w  = (const float*)d_in[6];
  const float* norm_b  = (const float*)d_in[7];
  const float* W_out   = (const float*)d_in[8];
  float* out = (float*)d_out;

  char* ws = (char*)d_ws;
  size_t off = 0;
  auto alloc = [&](size_t bytes) {
    void* p = ws + off;
    off += (bytes + 255) & ~(size_t)255;
    return p;
  };
  unsigned short* zxbcdt = (unsigned short*)alloc((size_t)kRows * kDProj * 2);        // 71.8 MB
  unsigned short* xbc    = (unsigned short*)alloc((size_t)kRows * kConvDim * 2);      // 37.7 MB
  float* dtb             = (float*)alloc((size_t)kRows * kNH * 4);                    //  1.0 MB
  float* asum            = (float*)alloc((size_t)kB * kNC * kNH * 4);                 // 16 KB
  unsigned short* A1     = (unsigned short*)alloc((size_t)kRows * 1024 * 2);          // 16.8 MB
  unsigned short* Bt1    = (unsigned short*)alloc((size_t)kDProjP * 1024 * 2);        //  9.2 MB
  unsigned short* states = (unsigned short*)alloc((size_t)kB * kNC * kNH * kHP * kDS * 2); // 67.1 MB
  unsigned short* Bt2    = (unsigned short*)alloc((size_t)1024 * kDI * 2);            //  4.2 MB
  unsigned short* ybuf   = (unsigned short*)alloc((size_t)kRows * kDI * 2);           // 33.6 MB
  float* mu              = (float*)alloc((size_t)kRows * 4);                          // 32 KB
  float* rstd            = (float*)alloc((size_t)kRows * 4);                          // 32 KB
  float* t1              = (float*)alloc(1024 * 4);
  float* t2              = (float*)alloc(1024 * 4);
  (void)ws_size; (void)in_sizes; (void)n_in; (void)out_size;

  // prep: casts / transposes / colsums (independent of pipeline order)
  cast_kernel<<<(kRows * 1024 / 4 + 255) / 256, 256, 0, stream>>>(
      (const float4*)u, (ushort4*)A1, kRows * 1024 / 4);
  transpose_cast<<<dim3(kDProjP / 32, 1024 / 32), 256, 0, stream>>>(
      W_in, Bt1, 1024, kDProj, nullptr);
  transpose_cast<<<dim3(1024 / 32, 2048 / 32), 256, 0, stream>>>(
      W_out, Bt2, 2048, 1024, norm_w);   // fold norm_w into Bt2
  colsum_kernel<<<16, 256, 0, stream>>>(W_out, norm_w, norm_b, t1, t2);
  // K1: zxbcdt = u @ W_in
  gemm_bt<unsigned short, false><<<dim3(kDProjP / 128, kRows / 128), 256, 0, stream>>>(
      A1, Bt1, zxbcdt, kRows, kDProj, 1024, nullptr, nullptr, nullptr, nullptr);
  // K2: dt
  dt_kernel<<<(kRows * kNH + 255) / 256, 256, 0, stream>>>(zxbcdt, dt_bias, dtb);
  // K3: conv + silu (8 rows/thread)
  conv_silu_kernel<<<dim3((kConvDim + 255) / 256, kRows / 8), 256, 0, stream>>>(
      zxbcdt, conv_w, conv_b, xbc);
  // K4: per-chunk states
  chunk_state_kernel<<<kB * kNC * kNH, 256, 0, stream>>>(xbc, dtb, A_log, states, asum);
  // K5: inter-chunk scan
  scan_kernel<<<kB * kNH * 8, 256, 0, stream>>>(states, asum);
  // K6: Y + gate, 4 heads/block
  y_kernel<<<kB * kNC * 8, 256, 0, stream>>>(xbc, zxbcdt, states, dtb, A_log, ybuf);
  // K7: LN stats
  rowstat_kernel<<<kRows, 256, 0, stream>>>(ybuf, mu, rstd);
  // K8: out = LN(y) @ W_out  (LN folded into epilogue)
  gemm_bt<float, true><<<dim3(1024 / 128, kRows / 128), 256, 0, stream>>>(
      ybuf, Bt2, out, kRows, 1024, 2048, mu, rstd, t1, t2);
}

// Round 6
// 457.742 us; speedup vs baseline: 6.5421x; 1.0419x over previous
//
#include <hip/hip_runtime.h>
#include <hip/hip_bf16.h>
#include <math.h>

// ---------------------------------------------------------------------------
// Mamba2 forward, MI355X. Round 6:
//  - gemm_bt: XOR-swizzled LDS layout (global k-group g of row r stored at
//    position g^((r>>1)&3)) — kills the 8-way b128 read bank conflict.
//  - y_kernel emits per-block LN partial sums (deterministic, no atomics);
//    ln_reduce computes mu/rstd; rowstat pass deleted.
//  - LayerNorm stays folded into K8 epilogue.
// ---------------------------------------------------------------------------

namespace {

constexpr int kB   = 2;
constexpr int kL   = 4096;
constexpr int kDI  = 2048;
constexpr int kDS  = 128;
constexpr int kNH  = 32;
constexpr int kHP  = 64;
constexpr int kDC  = 4;
constexpr int kCS  = 64;
constexpr int kNC  = kL / kCS;
constexpr int kDProj   = 2 * kDI + 2 * kDS + kNH;  // 4384
constexpr int kDProjP  = 4480;                     // 35*128
constexpr int kConvDim = kDI + 2 * kDS;            // 2304
constexpr int kRows = kB * kL;                     // 8192
constexpr float kEps = 1e-5f;
constexpr int kTS = 136;   // LDS stride for [64][128] tiles
constexpr int kWS = 72;    // LDS stride for [64][64] tiles

typedef __bf16 bf16x8 __attribute__((ext_vector_type(8)));
typedef float f32x4 __attribute__((ext_vector_type(4)));
typedef unsigned short ushort8 __attribute__((ext_vector_type(8)));

__device__ inline float bu2f(unsigned short u) {
  union { unsigned int i; float f; } x; x.i = ((unsigned int)u) << 16; return x.f;
}
__device__ inline unsigned short f2bu(float f) {
  __hip_bfloat16 h = __float2bfloat16(f);
  return *reinterpret_cast<unsigned short*>(&h);
}

__device__ inline void store_out(float* C, size_t i, float v) { C[i] = v; }
__device__ inline void store_out(unsigned short* C, size_t i, float v) { C[i] = f2bu(v); }

__device__ inline void gld_lds16(const unsigned short* g, unsigned short* l) {
  __builtin_amdgcn_global_load_lds(
      (const __attribute__((address_space(1))) unsigned int*)g,
      (__attribute__((address_space(3))) unsigned int*)l, 16, 0, 0);
}

// ---- cast fp32 -> bf16
__global__ void cast_kernel(const float4* __restrict__ in, ushort4* __restrict__ out, int n4) {
  int i = blockIdx.x * 256 + threadIdx.x;
  if (i >= n4) return;
  float4 v = in[i];
  ushort4 o;
  o.x = f2bu(v.x); o.y = f2bu(v.y); o.z = f2bu(v.z); o.w = f2bu(v.w);
  out[i] = o;
}

// ---- transpose + cast (+optional per-row scale): in[R][C] fp32 -> out[Cpad][R] bf16
__global__ void transpose_cast(const float* __restrict__ in, unsigned short* __restrict__ out,
                               int R, int C, const float* __restrict__ scale) {
  __shared__ float t[32][33];
  const int c0 = blockIdx.x * 32;
  const int r0 = blockIdx.y * 32;
  const int tx = threadIdx.x & 31, ty = threadIdx.x >> 5;
  for (int rr = ty; rr < 32; rr += 8) {
    int c = c0 + tx;
    float v = (c < C) ? in[(size_t)(r0 + rr) * C + c] : 0.f;
    if (scale) v *= scale[r0 + rr];
    t[rr][tx] = v;
  }
  __syncthreads();
  for (int cc = ty; cc < 32; cc += 8) {
    int orow = c0 + cc;
    out[(size_t)orow * R + r0 + tx] = f2bu(t[tx][cc]);
  }
}

// ---- t1[n] = sum_k w[k]*W2[k][n], t2[n] = sum_k b[k]*W2[k][n]
__global__ void colsum_kernel(const float* __restrict__ W2, const float* __restrict__ wv,
                              const float* __restrict__ bv,
                              float* __restrict__ t1, float* __restrict__ t2) {
  __shared__ float p1[4][64], p2[4][64];
  const int nl = threadIdx.x & 63;
  const int ks = threadIdx.x >> 6;
  const int n = blockIdx.x * 64 + nl;
  float s1 = 0.f, s2 = 0.f;
  for (int k = ks * 512; k < ks * 512 + 512; k++) {
    float v = W2[(size_t)k * 1024 + n];
    s1 += wv[k] * v;
    s2 += bv[k] * v;
  }
  p1[ks][nl] = s1; p2[ks][nl] = s2;
  __syncthreads();
  if (threadIdx.x < 64) {
    t1[blockIdx.x * 64 + threadIdx.x] =
        p1[0][threadIdx.x] + p1[1][threadIdx.x] + p1[2][threadIdx.x] + p1[3][threadIdx.x];
    t2[blockIdx.x * 64 + threadIdx.x] =
        p2[0][threadIdx.x] + p2[1][threadIdx.x] + p2[2][threadIdx.x] + p2[3][threadIdx.x];
  }
}

// ---- MFMA GEMM with XOR-swizzled LDS. FOLD applies LayerNorm in epilogue.
template <typename OutT, bool FOLD>
__global__ __launch_bounds__(256) void gemm_bt(const unsigned short* __restrict__ A,
                                               const unsigned short* __restrict__ Bt,
                                               OutT* __restrict__ C, int M, int N, int K,
                                               const float* __restrict__ mu,
                                               const float* __restrict__ rstd,
                                               const float* __restrict__ t1,
                                               const float* __restrict__ t2) {
  __shared__ __align__(16) unsigned short As[128 * 32];
  __shared__ __align__(16) unsigned short Bs[128 * 32];
  const int tid = threadIdx.x;
  const int wave = tid >> 6, lane = tid & 63;
  const int m0 = blockIdx.y * 128, n0 = blockIdx.x * 128;
  const int wr = (wave >> 1) * 64, wc = (wave & 1) * 64;
  const int st_row = lane >> 2;
  // swizzle: k-group g of row r lives at LDS position g ^ ((r>>1)&3)
  const int st_col = (((lane & 3) ^ ((st_row >> 1) & 3))) * 8;
  const unsigned short* pA[2];
  const unsigned short* pB[2];
  unsigned short* lA[2];
  unsigned short* lB[2];
#pragma unroll
  for (int r = 0; r < 2; r++) {
    int q = wave * 2 + r;
    pA[r] = A + (size_t)(m0 + q * 16 + st_row) * K + st_col;
    pB[r] = Bt + (size_t)(n0 + q * 16 + st_row) * K + st_col;
    lA[r] = &As[q * 512];
    lB[r] = &Bs[q * 512];
  }
  const int frag_row = lane & 15;
  const int rk = (((lane >> 4) ^ ((frag_row >> 1) & 3))) * 8;  // swizzled read pos
  f32x4 acc[4][4] = {};
  for (int k0 = 0; k0 < K; k0 += 32) {
#pragma unroll
    for (int r = 0; r < 2; r++) {
      gld_lds16(pA[r] + k0, lA[r]);
      gld_lds16(pB[r] + k0, lB[r]);
    }
    asm volatile("s_waitcnt vmcnt(0)" ::: "memory");
    __syncthreads();
    bf16x8 af[4], bfr[4];
#pragma unroll
    for (int i = 0; i < 4; i++)
      af[i] = *(const bf16x8*)&As[(wr + i * 16 + frag_row) * 32 + rk];
#pragma unroll
    for (int j = 0; j < 4; j++)
      bfr[j] = *(const bf16x8*)&Bs[(wc + j * 16 + frag_row) * 32 + rk];
#pragma unroll
    for (int i = 0; i < 4; i++)
#pragma unroll
      for (int j = 0; j < 4; j++)
        acc[i][j] = __builtin_amdgcn_mfma_f32_16x16x32_bf16(af[i], bfr[j], acc[i][j], 0, 0, 0);
    __syncthreads();
  }
  const int crow = (lane >> 4) * 4;
  const int ccol = lane & 15;
#pragma unroll
  for (int i = 0; i < 4; i++) {
#pragma unroll
    for (int j = 0; j < 4; j++) {
      int n = n0 + wc + j * 16 + ccol;
      if (n < N) {
        float c1 = FOLD ? t1[n] : 0.f;
        float c2 = FOLD ? t2[n] : 0.f;
#pragma unroll
        for (int r = 0; r < 4; r++) {
          int m = m0 + wr + i * 16 + crow + r;
          float v = acc[i][j][r];
          if (FOLD) v = rstd[m] * (v - mu[m] * c1) + c2;
          store_out(C, (size_t)m * N + n, v);
        }
      }
    }
  }
}

// ---- K2: dt = softplus(dt_raw + dt_bias)
__global__ void dt_kernel(const unsigned short* __restrict__ zxbcdt,
                          const float* __restrict__ dt_bias,
                          float* __restrict__ dtbuf) {
  int idx = blockIdx.x * 256 + threadIdx.x;
  if (idx >= kRows * kNH) return;
  int row = idx >> 5, h = idx & 31;
  float x = bu2f(zxbcdt[(size_t)row * kDProj + (kDProj - kNH) + h]) + dt_bias[h];
  dtbuf[idx] = (x > 15.f) ? x : log1pf(expf(x));
}

// ---- K3: causal depthwise conv (k=4) + SiLU, 8 rows/thread
__global__ void conv_silu_kernel(const unsigned short* __restrict__ zxbcdt,
                                 const float* __restrict__ conv_w,
                                 const float* __restrict__ conv_b,
                                 unsigned short* __restrict__ xbc_act) {
  int c = blockIdx.x * 256 + threadIdx.x;
  if (c >= kConvDim) return;
  const int r0 = blockIdx.y * 8;
  const int l0 = r0 & (kL - 1);
  const float w0 = conv_w[c * 4], w1 = conv_w[c * 4 + 1];
  const float w2 = conv_w[c * 4 + 2], w3 = conv_w[c * 4 + 3];
  const float bias = conv_b[c];
  float v[11];
#pragma unroll
  for (int i = 0; i < 11; i++) {
    int l = l0 - 3 + i;
    v[i] = (l >= 0) ? bu2f(zxbcdt[(size_t)(r0 - 3 + i) * kDProj + kDI + c]) : 0.f;
  }
#pragma unroll
  for (int j = 0; j < 8; j++) {
    float a = bias + v[j] * w0 + v[j + 1] * w1 + v[j + 2] * w2 + v[j + 3] * w3;
    xbc_act[(size_t)(r0 + j) * kConvDim + c] = f2bu(a / (1.f + expf(-a)));
  }
}

// ---- K4: per-(b,chunk,head) end-of-chunk state via MFMA
__global__ __launch_bounds__(256) void chunk_state_kernel(
    const unsigned short* __restrict__ xbc_act,
    const float* __restrict__ dtbuf,
    const float* __restrict__ A_log,
    unsigned short* __restrict__ states,
    float* __restrict__ asum) {
  const int id = blockIdx.x;
  const int h = id & 31;
  const int c = (id >> 5) & (kNC - 1);
  const int b = id >> 11;
  const int tid = threadIdx.x;
  const int wave = tid >> 6, lane = tid & 63;
  __shared__ __align__(16) unsigned short sBT[kDS * kWS];
  __shared__ __align__(16) unsigned short sxd[kCS * kWS];
  __shared__ float s_dt[kCS];
  __shared__ float s_acum[kCS];
  const int l0 = b * kL + c * kCS;
  if (tid < kCS) s_dt[tid] = dtbuf[(size_t)(l0 + tid) * kNH + h];
  __syncthreads();
  if (tid == 0) {
    float A = -expf(A_log[h]);
    float run = 0.f;
    for (int s = 0; s < kCS; s++) { run += A * s_dt[s]; s_acum[s] = run; }
    asum[id] = run;
  }
  __syncthreads();
  const float total = s_acum[kCS - 1];
  for (int e = tid; e < kCS * kDS; e += 256) {
    int s = e >> 7, n = e & 127;
    sBT[n * kWS + s] = xbc_act[(size_t)(l0 + s) * kConvDim + kDI + n];
  }
  for (int e = tid; e < kCS * kHP; e += 256) {
    int s = e >> 6, p = e & 63;
    float xv = bu2f(xbc_act[(size_t)(l0 + s) * kConvDim + h * kHP + p]);
    sxd[p * kWS + s] = f2bu(xv * s_dt[s] * expf(total - s_acum[s]));
  }
  __syncthreads();
  const int arow = wave * 16 + (lane & 15);
  const int fk = (lane >> 4) * 8;
  f32x4 acc[8] = {};
#pragma unroll
  for (int kk = 0; kk < 2; kk++) {
    bf16x8 a = *(const bf16x8*)&sxd[arow * kWS + kk * 32 + fk];
#pragma unroll
    for (int j = 0; j < 8; j++) {
      bf16x8 bb = *(const bf16x8*)&sBT[(j * 16 + (lane & 15)) * kWS + kk * 32 + fk];
      acc[j] = __builtin_amdgcn_mfma_f32_16x16x32_bf16(a, bb, acc[j], 0, 0, 0);
    }
  }
  const int prow = wave * 16 + (lane >> 4) * 4;
  const int ncol = lane & 15;
  size_t base = (size_t)id * (kHP * kDS);
#pragma unroll
  for (int j = 0; j < 8; j++)
#pragma unroll
    for (int r = 0; r < 4; r++)
      states[base + (size_t)(prow + r) * kDS + j * 16 + ncol] = f2bu(acc[j][r]);
}

// ---- K5: sequential inter-chunk scan, vectorized ushort4
__global__ void scan_kernel(unsigned short* __restrict__ states,
                            const float* __restrict__ asum) {
  const int blk = blockIdx.x;
  const int seg = blk & 7;
  const int bh = blk >> 3;
  const int h = bh & 31, b = bh >> 5;
  const int e4 = seg * 256 + threadIdx.x;
  float c0 = 0.f, c1 = 0.f, c2 = 0.f, c3 = 0.f;
  for (int c = 0; c < kNC; c++) {
    const int id = (b * kNC + c) * kNH + h;
    ushort4* p = (ushort4*)states + (size_t)id * 2048 + e4;
    float decay = expf(asum[id]);
    ushort4 t = *p;
    ushort4 o;
    o.x = f2bu(c0); o.y = f2bu(c1); o.z = f2bu(c2); o.w = f2bu(c3);
    *p = o;
    c0 = c0 * decay + bu2f(t.x);
    c1 = c1 * decay + bu2f(t.y);
    c2 = c2 * decay + bu2f(t.z);
    c3 = c3 * decay + bu2f(t.w);
  }
}

// ---- K6: intra-chunk Y, 4 heads/block, emits LN partial sums per row
__global__ __launch_bounds__(256) void y_kernel(
    const unsigned short* __restrict__ xbc_act,
    const unsigned short* __restrict__ zxbcdt,
    const unsigned short* __restrict__ states_in,
    const float* __restrict__ dtbuf,
    const float* __restrict__ A_log,
    unsigned short* __restrict__ ybuf,
    float* __restrict__ pS, float* __restrict__ pQ) {
  const int id = blockIdx.x;                 // (b*NC + c)*8 + hg
  const int hg = id & 7;
  const int c = (id >> 3) & (kNC - 1);
  const int b = id >> 9;
  const int tid = threadIdx.x;
  const int wave = tid >> 6, lane = tid & 63;
  __shared__ __align__(16) unsigned short sC[kCS * kTS];
  __shared__ __align__(16) unsigned short sB[kCS * kTS];
  __shared__ __align__(16) unsigned short sxd[kCS * kWS];
  __shared__ __align__(16) unsigned short sW[kCS * kWS];
  __shared__ float s_dt[4][kCS];
  __shared__ float s_acum[4][kCS];
  const int l0 = b * kL + c * kCS;
  {
    int hh = tid >> 6, s = tid & 63;
    s_dt[hh][s] = dtbuf[(size_t)(l0 + s) * kNH + hg * 4 + hh];
  }
  __syncthreads();
  if (tid < 4) {
    float A = -expf(A_log[hg * 4 + tid]);
    float run = 0.f;
    for (int s = 0; s < kCS; s++) { run += A * s_dt[tid][s]; s_acum[tid][s] = run; }
  }
  for (int e = tid; e < kCS * 16; e += 256) {
    int row = e >> 4, c8 = (e & 15) * 8;
    size_t rb = (size_t)(l0 + row) * kConvDim;
    *(ushort8*)&sB[row * kTS + c8] = *(const ushort8*)&xbc_act[rb + kDI + c8];
    *(ushort8*)&sC[row * kTS + c8] = *(const ushort8*)&xbc_act[rb + kDI + kDS + c8];
  }
  __syncthreads();
  const int arow = wave * 16 + (lane & 15);
  const int fk = (lane >> 4) * 8;
  // G[l][s] = C . B^T  (K=128) — head-independent, once per block
  f32x4 accG[4] = {};
#pragma unroll
  for (int kk = 0; kk < 4; kk++) {
    bf16x8 a = *(const bf16x8*)&sC[arow * kTS + kk * 32 + fk];
#pragma unroll
    for (int j = 0; j < 4; j++) {
      bf16x8 bb = *(const bf16x8*)&sB[(j * 16 + (lane & 15)) * kTS + kk * 32 + fk];
      accG[j] = __builtin_amdgcn_mfma_f32_16x16x32_bf16(a, bb, accG[j], 0, 0, 0);
    }
  }
  const int lrow = wave * 16 + (lane >> 4) * 4;
  const size_t sbase = (size_t)((b * kNC + c) * kNH) * (kHP * kDS);
  float rS[4] = {}, rQ[4] = {};
  for (int hh = 0; hh < 4; hh++) {
    const int h = hg * 4 + hh;
    __syncthreads();
    for (int e = tid; e < kCS * kHP; e += 256) {
      int s = e >> 6, p = e & 63;
      float xv = bu2f(xbc_act[(size_t)(l0 + s) * kConvDim + h * kHP + p]);
      sxd[p * kWS + s] = f2bu(xv * s_dt[hh][s]);
    }
#pragma unroll
    for (int j = 0; j < 4; j++) {
      int scol = j * 16 + (lane & 15);
      float as = s_acum[hh][scol];
#pragma unroll
      for (int r = 0; r < 4; r++) {
        int l = lrow + r;
        float w = (scol <= l) ? accG[j][r] * expf(s_acum[hh][l] - as) : 0.f;
        sW[l * kWS + scol] = f2bu(w);
      }
    }
    for (int e = tid; e < kCS * 16; e += 256) {
      int row = e >> 4, c8 = (e & 15) * 8;
      *(ushort8*)&sB[row * kTS + c8] =
          *(const ushort8*)&states_in[sbase + (size_t)h * (kHP * kDS) + row * kDS + c8];
    }
    __syncthreads();
    f32x4 accY[4] = {};
#pragma unroll
    for (int kk = 0; kk < 2; kk++) {
      bf16x8 a = *(const bf16x8*)&sW[arow * kWS + kk * 32 + fk];
#pragma unroll
      for (int j = 0; j < 4; j++) {
        bf16x8 bb = *(const bf16x8*)&sxd[(j * 16 + (lane & 15)) * kWS + kk * 32 + fk];
        accY[j] = __builtin_amdgcn_mfma_f32_16x16x32_bf16(a, bb, accY[j], 0, 0, 0);
      }
    }
    f32x4 accO[4] = {};
#pragma unroll
    for (int kk = 0; kk < 4; kk++) {
      bf16x8 a = *(const bf16x8*)&sC[arow * kTS + kk * 32 + fk];
#pragma unroll
      for (int j = 0; j < 4; j++) {
        bf16x8 bb = *(const bf16x8*)&sB[(j * 16 + (lane & 15)) * kTS + kk * 32 + fk];
        accO[j] = __builtin_amdgcn_mfma_f32_16x16x32_bf16(a, bb, accO[j], 0, 0, 0);
      }
    }
#pragma unroll
    for (int r = 0; r < 4; r++) {
      int l = lrow + r;
      float el = expf(s_acum[hh][l]);
      size_t zrow = (size_t)(l0 + l) * kDProj + h * kHP;
      size_t yrow = (size_t)(l0 + l) * kDI + h * kHP;
#pragma unroll
      for (int j = 0; j < 4; j++) {
        int p = j * 16 + (lane & 15);
        float yv = accY[j][r] + el * accO[j][r];
        float z = bu2f(zxbcdt[zrow + p]);
        yv *= z / (1.f + expf(-z));
        rS[r] += yv;
        rQ[r] += yv * yv;
        ybuf[yrow + p] = f2bu(yv);
      }
    }
  }
  // reduce LN partials across the 16 lanes sharing each row, write per-block slot
#pragma unroll
  for (int m = 1; m < 16; m <<= 1) {
#pragma unroll
    for (int r = 0; r < 4; r++) {
      rS[r] += __shfl_xor(rS[r], m);
      rQ[r] += __shfl_xor(rQ[r], m);
    }
  }
  if ((lane & 15) == 0) {
#pragma unroll
    for (int r = 0; r < 4; r++) {
      int row = l0 + lrow + r;
      pS[(size_t)row * 8 + hg] = rS[r];
      pQ[(size_t)row * 8 + hg] = rQ[r];
    }
  }
}

// ---- K7: finalize LN stats from per-block partials
__global__ void ln_reduce(const float* __restrict__ pS, const float* __restrict__ pQ,
                          float* __restrict__ mu, float* __restrict__ rstd) {
  int row = blockIdx.x * 256 + threadIdx.x;
  if (row >= kRows) return;
  float s = 0.f, q = 0.f;
#pragma unroll
  for (int i = 0; i < 8; i++) { s += pS[(size_t)row * 8 + i]; q += pQ[(size_t)row * 8 + i]; }
  float m = s / kDI;
  mu[row] = m;
  rstd[row] = rsqrtf(q / kDI - m * m + kEps);
}

}  // namespace

extern "C" void kernel_launch(void* const* d_in, const int* in_sizes, int n_in,
                              void* d_out, int out_size, void* d_ws, size_t ws_size,
                              hipStream_t stream) {
  const float* u       = (const float*)d_in[0];
  const float* W_in    = (const float*)d_in[1];
  const float* conv_w  = (const float*)d_in[2];
  const float* conv_b  = (const float*)d_in[3];
  const float* dt_bias = (const float*)d_in[4];
  const float* A_log   = (const float*)d_in[5];
  const float* norm_w  = (const float*)d_in[6];
  const float* norm_b  = (const float*)d_in[7];
  const float* W_out   = (const float*)d_in[8];
  float* out = (float*)d_out;

  char* ws = (char*)d_ws;
  size_t off = 0;
  auto alloc = [&](size_t bytes) {
    void* p = ws + off;
    off += (bytes + 255) & ~(size_t)255;
    return p;
  };
  unsigned short* zxbcdt = (unsigned short*)alloc((size_t)kRows * kDProj * 2);        // 71.8 MB
  unsigned short* xbc    = (unsigned short*)alloc((size_t)kRows * kConvDim * 2);      // 37.7 MB
  float* dtb             = (float*)alloc((size_t)kRows * kNH * 4);                    //  1.0 MB
  float* asum            = (float*)alloc((size_t)kB * kNC * kNH * 4);                 // 16 KB
  unsigned short* A1     = (unsigned short*)alloc((size_t)kRows * 1024 * 2);          // 16.8 MB
  unsigned short* Bt1    = (unsigned short*)alloc((size_t)kDProjP * 1024 * 2);        //  9.2 MB
  unsigned short* states = (unsigned short*)alloc((size_t)kB * kNC * kNH * kHP * kDS * 2); // 67.1 MB
  unsigned short* Bt2    = (unsigned short*)alloc((size_t)1024 * kDI * 2);            //  4.2 MB
  unsigned short* ybuf   = (unsigned short*)alloc((size_t)kRows * kDI * 2);           // 33.6 MB
  float* mu              = (float*)alloc((size_t)kRows * 4);
  float* rstd            = (float*)alloc((size_t)kRows * 4);
  float* t1              = (float*)alloc(1024 * 4);
  float* t2              = (float*)alloc(1024 * 4);
  float* pS              = (float*)alloc((size_t)kRows * 8 * 4);                      // 256 KB
  float* pQ              = (float*)alloc((size_t)kRows * 8 * 4);                      // 256 KB
  (void)ws_size; (void)in_sizes; (void)n_in; (void)out_size;

  cast_kernel<<<(kRows * 1024 / 4 + 255) / 256, 256, 0, stream>>>(
      (const float4*)u, (ushort4*)A1, kRows * 1024 / 4);
  transpose_cast<<<dim3(kDProjP / 32, 1024 / 32), 256, 0, stream>>>(
      W_in, Bt1, 1024, kDProj, nullptr);
  transpose_cast<<<dim3(1024 / 32, 2048 / 32), 256, 0, stream>>>(
      W_out, Bt2, 2048, 1024, norm_w);
  colsum_kernel<<<16, 256, 0, stream>>>(W_out, norm_w, norm_b, t1, t2);
  gemm_bt<unsigned short, false><<<dim3(kDProjP / 128, kRows / 128), 256, 0, stream>>>(
      A1, Bt1, zxbcdt, kRows, kDProj, 1024, nullptr, nullptr, nullptr, nullptr);
  dt_kernel<<<(kRows * kNH + 255) / 256, 256, 0, stream>>>(zxbcdt, dt_bias, dtb);
  conv_silu_kernel<<<dim3((kConvDim + 255) / 256, kRows / 8), 256, 0, stream>>>(
      zxbcdt, conv_w, conv_b, xbc);
  chunk_state_kernel<<<kB * kNC * kNH, 256, 0, stream>>>(xbc, dtb, A_log, states, asum);
  scan_kernel<<<kB * kNH * 8, 256, 0, stream>>>(states, asum);
  y_kernel<<<kB * kNC * 8, 256, 0, stream>>>(xbc, zxbcdt, states, dtb, A_log, ybuf, pS, pQ);
  ln_reduce<<<kRows / 256, 256, 0, stream>>>(pS, pQ, mu, rstd);
  gemm_bt<float, true><<<dim3(1024 / 128, kRows / 128), 256, 0, stream>>>(
      ybuf, Bt2, out, kRows, 1024, 2048, mu, rstd, t1, t2);
}